// Round 22
// baseline (1087.734 us; speedup 1.0000x reference)
//
#include <hip/hip_runtime.h>
#include <stdint.h>

// BinarizeLinear inference: out = sign(X) @ sign(W) + bias
// Round 22: occupancy push. (1) GEMM back to BK=64 / 36 KiB LDS geometry
// (r20) but __launch_bounds__(256, 4): 4 blocks/CU co-resident (144 KiB LDS,
// VGPR 84 <= 128 cap) -- grid 1024 = one full generation, cross-block TLP
// fills each block's barrier/lgkm stalls (m114 mechanism). (2) Both converts
// merged into ONE kernel (wave-uniform branch) -- saves a launch + gap.
// fp4 e2m1 +-1 exact; counted vmcnt(3) 3-deep pipeline. absmax 0.

#define N_ROWS 8192
#define K_DIM  4096
#define O_DIM  4096
#define KW     64

typedef int   int4v    __attribute__((ext_vector_type(4)));
typedef int   int8v    __attribute__((ext_vector_type(8)));
typedef float float16v __attribute__((ext_vector_type(16)));

// fp4 operand: low 4 regs carry data, high 4 undef (FMT=fp4 ignores them)
__device__ __forceinline__ int8v mk8u(int4v x) {
    return __builtin_shufflevector(x, x, 0, 1, 2, 3, -1, -1, -1, -1);
}

// fp4 e2m1: +1.0 = 0x2, -1.0 = 0xA
__device__ __forceinline__ uint32_t nib4(float f) { return f > 0.0f ? 0x2u : 0xAu; }

// ====================== X and W -> fp4 blocked, ONE kernel ==================
// Pieces: u in [0,16384) -> X piece; u-16384 in [0,8192) -> W piece.
// Layout per operand: [G][kt][g][lane][16B], piece = 1 KiB (one wave-write).
__global__ __launch_bounds__(256) void convert_xw_fp4(
        const float* __restrict__ X, const float* __restrict__ W,
        uint8_t* __restrict__ XB, uint8_t* __restrict__ WB) {
    int u    = blockIdx.x * 4 + (threadIdx.x >> 6);
    int lane = threadIdx.x & 63;

    if (u < 16384) {                         // ---- X piece ----
        int g = u & 7, kt = (u >> 3) & 63, G = u >> 9;
        int row = G * 256 + g * 32 + (lane & 31);
        int k0  = kt * 64 + (lane >> 5) * 32;
        const float4* src = (const float4*)(X + (size_t)row * K_DIM + k0);
        uint32_t ow[4];
        #pragma unroll
        for (int q = 0; q < 4; ++q) {
            float4 vA = src[2 * q];
            float4 vB = src[2 * q + 1];
            uint32_t b0 = nib4(vA.x) | (nib4(vA.y) << 4);
            uint32_t b1 = nib4(vA.z) | (nib4(vA.w) << 4);
            uint32_t b2 = nib4(vB.x) | (nib4(vB.y) << 4);
            uint32_t b3 = nib4(vB.z) | (nib4(vB.w) << 4);
            ow[q] = b0 | (b1 << 8) | (b2 << 16) | (b3 << 24);
        }
        int4v o; o.x = (int)ow[0]; o.y = (int)ow[1]; o.z = (int)ow[2]; o.w = (int)ow[3];
        *(int4v*)(XB + (size_t)u * 1024 + lane * 16) = o;
    } else {                                 // ---- W piece ----
        int v = u - 16384;
        int g = v & 7, kt = (v >> 3) & 63, G = v >> 9;
        int o     = G * 256 + g * 32 + (lane & 31);
        int kbase = kt * 64 + (lane >> 5) * 32;
        const float* src = W + (size_t)kbase * O_DIM + o;
        uint32_t ow[4];
        #pragma unroll
        for (int q = 0; q < 4; ++q) {
            uint32_t x = 0;
            #pragma unroll
            for (int j = 0; j < 8; ++j) {
                float f = src[(size_t)(q * 8 + j) * O_DIM];
                x |= nib4(f) << (4 * j);
            }
            ow[q] = x;
        }
        int4v ov; ov.x = (int)ow[0]; ov.y = (int)ow[1]; ov.z = (int)ow[2]; ov.w = (int)ow[3];
        *(int4v*)(WB + (size_t)v * 1024 + lane * 16) = ov;
    }
}

// ====================== 256x128 fp4 GEMM, BK=64, 4 blocks/CU ================
#define MFMA4(a, b, c)                                                        \
    __builtin_amdgcn_mfma_scale_f32_32x32x64_f8f6f4(                          \
        (a), (b), (c), 4, 4, 0, 0x7F7F7F7F, 0, 0x7F7F7F7F)

__global__ __launch_bounds__(256, 4) void fp4_gemm_kernel(
        const uint8_t* __restrict__ XB, const uint8_t* __restrict__ WB,
        const float* __restrict__ bias, float* __restrict__ out) {
    __shared__ uint8_t lds[3 * 12288];   // 36 KiB -> 4 blocks/CU

    const int tid  = threadIdx.x;
    const int swzb = (blockIdx.x & 7) * 128 + (blockIdx.x >> 3);  // XCD swizzle
    const int brow = (swzb >> 5) * 256;
    const int bcol = (swzb & 31) * 128;

    const int lane = tid & 63;
    const int wid  = tid >> 6;
    const int wrow = (wid >> 1) * 128;   // 2 M-groups
    const int wcol = (wid & 1) * 64;     // 2 N-groups
    const int l31  = lane & 31;
    const int lh   = lane >> 5;

    const int abase = (wrow >> 5) * 1024 + lane * 16;          // A region
    const int bbase = 8192 + (wcol >> 5) * 1024 + lane * 16;   // B region

    const uint8_t* Asrc = XB + ((size_t)(brow >> 8) << 19) + tid * 16;
    const uint8_t* Bsrc = WB + ((size_t)(bcol >> 8) << 19)
                             + ((bcol & 255) >> 5) * 1024 + tid * 16;

#define GSTAGE(buf, t)                                                        \
    {                                                                         \
        _Pragma("unroll")                                                     \
        for (int j = 0; j < 2; ++j) {                                         \
            __builtin_amdgcn_global_load_lds(                                 \
                (const __attribute__((address_space(1))) void*)               \
                    (Asrc + (size_t)(t) * 8192 + j * 4096),                   \
                (__attribute__((address_space(3))) void*)                     \
                    (lds + (buf) * 12288 + j * 4096 + tid * 16), 16, 0, 0);   \
        }                                                                     \
        __builtin_amdgcn_global_load_lds(                                     \
            (const __attribute__((address_space(1))) void*)                   \
                (Bsrc + (size_t)(t) * 8192),                                  \
            (__attribute__((address_space(3))) void*)                         \
                (lds + (buf) * 12288 + 8192 + tid * 16), 16, 0, 0);           \
    }

#define LOADP(buf)                                                            \
    {                                                                         \
        const uint8_t* Ap = lds + (buf) * 12288 + abase;                      \
        const uint8_t* Bp = lds + (buf) * 12288 + bbase;                      \
        a0 = mk8u(*(const int4v*)(Ap));                                       \
        a1 = mk8u(*(const int4v*)(Ap + 1024));                                \
        a2 = mk8u(*(const int4v*)(Ap + 2048));                                \
        a3 = mk8u(*(const int4v*)(Ap + 3072));                                \
        b0 = mk8u(*(const int4v*)(Bp));                                       \
        b1 = mk8u(*(const int4v*)(Bp + 1024));                                \
    }

#define MFMA8()                                                               \
    {                                                                         \
        __builtin_amdgcn_s_setprio(1);                                        \
        c00 = MFMA4(a0, b0, c00);  c01 = MFMA4(a0, b1, c01);                  \
        c10 = MFMA4(a1, b0, c10);  c11 = MFMA4(a1, b1, c11);                  \
        c20 = MFMA4(a2, b0, c20);  c21 = MFMA4(a2, b1, c21);                  \
        c30 = MFMA4(a3, b0, c30);  c31 = MFMA4(a3, b1, c31);                  \
        __builtin_amdgcn_s_setprio(0);                                        \
    }

    // one pipeline step: wait -> barrier -> stage(t+2) -> read -> mfma
#define STEP(bufc, bufs, t, LASTWAIT)                                         \
    {                                                                         \
        if (LASTWAIT) asm volatile("s_waitcnt vmcnt(0)" ::: "memory");        \
        else          asm volatile("s_waitcnt vmcnt(3)" ::: "memory");        \
        __builtin_amdgcn_s_barrier();                                         \
        if ((t) + 2 < 64) GSTAGE(bufs, (t) + 2);                              \
        LOADP(bufc);                                                          \
        MFMA8();                                                              \
    }

    float16v c00 = 0, c01 = 0, c10 = 0, c11 = 0,
             c20 = 0, c21 = 0, c30 = 0, c31 = 0;
    int8v a0, a1, a2, a3, b0, b1;

    // prologue: stage steps 0,1 (6 loads in flight)
    GSTAGE(0, 0);
    GSTAGE(1, 1);

    // t = 0..62 in 21 statically-indexed triples; tail t = 63 (buf 0)
    for (int i = 0; i < 21; ++i) {
        const int t = 3 * i;
        STEP(0, 2, t,     false);
        STEP(1, 0, t + 1, false);
        STEP(2, 1, t + 2, false);
    }
    STEP(0, 2, 63, true);
#undef STEP
#undef MFMA8
#undef LOADP
#undef GSTAGE

    // epilogue: C/D map col=lane&31, row=(r&3)+8*(r>>2)+4*(lane>>5)
    float bv0 = bias[bcol + wcol + l31];
    float bv1 = bias[bcol + wcol + 32 + l31];
    const size_t obase = (size_t)(brow + wrow) * O_DIM + bcol + wcol;

#define CWRITE(cm, m, n, bv)                                                  \
    {                                                                         \
        _Pragma("unroll")                                                     \
        for (int r = 0; r < 16; ++r) {                                        \
            int rl = (r & 3) + 8 * (r >> 2) + 4 * lh;                         \
            out[obase + (size_t)((m) * 32 + rl) * O_DIM + (n) * 32 + l31] =   \
                cm[r] + (bv);                                                 \
        }                                                                     \
    }

    CWRITE(c00, 0, 0, bv0); CWRITE(c01, 0, 1, bv1);
    CWRITE(c10, 1, 0, bv0); CWRITE(c11, 1, 1, bv1);
    CWRITE(c20, 2, 0, bv0); CWRITE(c21, 2, 1, bv1);
    CWRITE(c30, 3, 0, bv0); CWRITE(c31, 3, 1, bv1);
#undef CWRITE
}

// ====================== popcount fallback (round-5, proven) =================
__global__ __launch_bounds__(256) void pack_x_kernel(
        const float* __restrict__ X, uint64_t* __restrict__ Xb) {
    int wave = (int)((blockIdx.x * blockDim.x + threadIdx.x) >> 6);
    int lane = threadIdx.x & 63;
    if (wave >= N_ROWS) return;
    const float* xr = X + (size_t)wave * K_DIM;
    uint64_t* xbr = Xb + (size_t)wave * KW;
    #pragma unroll 4
    for (int w = 0; w < KW; ++w) {
        float v = xr[w * 64 + lane];
        unsigned long long m = __ballot(v > 0.0f);
        if (lane == 0) xbr[w] = (uint64_t)m;
    }
}

__global__ __launch_bounds__(256) void pack_w_kernel(
        const float* __restrict__ W, uint64_t* __restrict__ Wb) {
    int oc = blockIdx.x & 15;
    int w  = blockIdx.x >> 4;
    int o  = oc * 256 + threadIdx.x;
    const float* wp = W + (size_t)(w * 64) * O_DIM + o;
    uint64_t word = 0;
    #pragma unroll 8
    for (int p = 0; p < 64; ++p) {
        float v = wp[(size_t)p * O_DIM];
        word |= (uint64_t)(v > 0.0f) << p;
    }
    Wb[(size_t)o * KW + w] = word;
}

__global__ __launch_bounds__(256) void xnor_gemm_kernel(
        const uint8_t* __restrict__ Xb, const uint8_t* __restrict__ Wb,
        const float* __restrict__ bias, float* __restrict__ out) {
    __shared__ uint4 lds4[2048];
    const int tid    = threadIdx.x;
    const int brow   = (blockIdx.x >> 5) * 128;
    const int bcol   = (blockIdx.x & 31) * 128;
    const int tx     = tid & 15;
    const int ty     = tid >> 4;
    const int widx   = tid >> 6;
    const int xbase0 = ty * 64 + (ty & 7);
    const int wbase0 = 1024 + tx * 64 + (tx & 7);
    uint32_t acc[8][8] = {};
    for (int kc = 0; kc < 4; ++kc) {
        __syncthreads();
        #pragma unroll
        for (int i = 0; i < 4; ++i) {
            int idx  = tid + 256 * i;
            int row  = idx >> 3;
            int srcc = (idx & 7) ^ ((idx >> 6) & 7);
            size_t goff = ((size_t)row << 9) + (kc << 7) + (srcc << 4);
            __builtin_amdgcn_global_load_lds(
                (const __attribute__((address_space(1))) void*)
                    (Xb + ((size_t)brow << 9) + goff),
                (__attribute__((address_space(3))) void*)
                    (lds4 + i * 256 + widx * 64), 16, 0, 0);
            __builtin_amdgcn_global_load_lds(
                (const __attribute__((address_space(1))) void*)
                    (Wb + ((size_t)bcol << 9) + goff),
                (__attribute__((address_space(3))) void*)
                    (lds4 + 1024 + i * 256 + widx * 64), 16, 0, 0);
        }
        asm volatile("s_waitcnt vmcnt(0)" ::: "memory");
        __syncthreads();
        for (int kq = 0; kq < 8; ++kq) {
            const uint4* xp = &lds4[xbase0 ^ kq];
            const uint4* wp = &lds4[wbase0 ^ kq];
            uint4 xq[8];
            #pragma unroll
            for (int r = 0; r < 8; ++r) xq[r] = xp[8 * r];
            #pragma unroll
            for (int c = 0; c < 8; ++c) {
                uint4 wv = wp[8 * c];
                #pragma unroll
                for (int r = 0; r < 8; ++r) {
                    uint32_t a = acc[r][c];
                    a = __builtin_popcount(xq[r].x ^ wv.x) + a;
                    a = __builtin_popcount(xq[r].y ^ wv.y) + a;
                    a = __builtin_popcount(xq[r].z ^ wv.z) + a;
                    a = __builtin_popcount(xq[r].w ^ wv.w) + a;
                    acc[r][c] = a;
                }
            }
        }
    }
    float bv[8];
    #pragma unroll
    for (int c = 0; c < 8; ++c) bv[c] = bias[bcol + tx * 8 + c];
    #pragma unroll
    for (int r = 0; r < 8; ++r) {
        float vals[8];
        #pragma unroll
        for (int c = 0; c < 8; ++c)
            vals[c] = (float)(K_DIM - 2 * (int)acc[r][c]) + bv[c];
        float4* op = (float4*)(out + (size_t)(brow + ty * 8 + r) * O_DIM
                               + bcol + tx * 8);
        op[0] = make_float4(vals[0], vals[1], vals[2], vals[3]);
        op[1] = make_float4(vals[4], vals[5], vals[6], vals[7]);
    }
}

// ====================== launcher ============================================
extern "C" void kernel_launch(void* const* d_in, const int* in_sizes, int n_in,
                              void* d_out, int out_size, void* d_ws, size_t ws_size,
                              hipStream_t stream) {
    const float* X    = (const float*)d_in[0];
    const float* W    = (const float*)d_in[1];
    const float* bias = (const float*)d_in[2];
    float* out        = (float*)d_out;

    const size_t XB4 = (size_t)N_ROWS * K_DIM / 2;   // 16 MiB fp4 X
    const size_t WB4 = (size_t)O_DIM * K_DIM / 2;    //  8 MiB fp4 W

    if (ws_size >= XB4 + WB4) {
        uint8_t* XBlk = (uint8_t*)d_ws;
        uint8_t* WBlk = (uint8_t*)d_ws + XB4;

        convert_xw_fp4<<<(16384 + 8192) / 4, 256, 0, stream>>>(X, W, XBlk, WBlk);
        fp4_gemm_kernel<<<(N_ROWS / 256) * (O_DIM / 128), 256, 0, stream>>>(
            XBlk, WBlk, bias, out);
    } else {
        uint64_t* Xb = (uint64_t*)d_ws;
        uint64_t* Wb = (uint64_t*)((uint8_t*)d_ws + (size_t)N_ROWS * KW * 8);
        pack_x_kernel<<<N_ROWS / 4, 256, 0, stream>>>(X, Xb);
        pack_w_kernel<<<16 * 64, 256, 0, stream>>>(W, Wb);
        xnor_gemm_kernel<<<(N_ROWS / 128) * (O_DIM / 128), 256, 0, stream>>>(
            (const uint8_t*)Xb, (const uint8_t*)Wb, bias, out);
    }
}

// Round 23
// 126.170 us; speedup vs baseline: 8.6211x; 8.6211x over previous
//
#include <hip/hip_runtime.h>
#include <stdint.h>

// BinarizeLinear inference: out = sign(X) @ sign(W) + bias
// Round 23: best-known combination. GEMM = round-21 exact (BK=128, 3-deep
// counted vmcnt(6), 72 KiB LDS, launch_bounds(256,2) -- r22 proved >2
// blocks/CU spills the 128 AGPR accumulators). Convert = round-22's merged
// single kernel (X and W in one dispatch, saves a launch + gap).
// fp4 e2m1 +-1 exact arithmetic throughout; absmax 0.

#define N_ROWS 8192
#define K_DIM  4096
#define O_DIM  4096
#define KW     64

typedef int   int4v    __attribute__((ext_vector_type(4)));
typedef int   int8v    __attribute__((ext_vector_type(8)));
typedef float float16v __attribute__((ext_vector_type(16)));

// fp4 operand: low 4 regs carry data, high 4 undef (FMT=fp4 ignores them)
__device__ __forceinline__ int8v mk8u(int4v x) {
    return __builtin_shufflevector(x, x, 0, 1, 2, 3, -1, -1, -1, -1);
}

// fp4 e2m1: +1.0 = 0x2, -1.0 = 0xA
__device__ __forceinline__ uint32_t nib4(float f) { return f > 0.0f ? 0x2u : 0xAu; }

// ====================== X and W -> fp4 blocked, ONE kernel ==================
// Pieces: u in [0,16384) -> X piece; u-16384 in [0,8192) -> W piece.
// Layout per operand: [G][kt][g][lane][16B], piece = 1 KiB (one wave-write).
__global__ __launch_bounds__(256) void convert_xw_fp4(
        const float* __restrict__ X, const float* __restrict__ W,
        uint8_t* __restrict__ XB, uint8_t* __restrict__ WB) {
    int u    = blockIdx.x * 4 + (threadIdx.x >> 6);
    int lane = threadIdx.x & 63;

    if (u < 16384) {                         // ---- X piece ----
        int g = u & 7, kt = (u >> 3) & 63, G = u >> 9;
        int row = G * 256 + g * 32 + (lane & 31);
        int k0  = kt * 64 + (lane >> 5) * 32;
        const float4* src = (const float4*)(X + (size_t)row * K_DIM + k0);
        uint32_t ow[4];
        #pragma unroll
        for (int q = 0; q < 4; ++q) {
            float4 vA = src[2 * q];
            float4 vB = src[2 * q + 1];
            uint32_t b0 = nib4(vA.x) | (nib4(vA.y) << 4);
            uint32_t b1 = nib4(vA.z) | (nib4(vA.w) << 4);
            uint32_t b2 = nib4(vB.x) | (nib4(vB.y) << 4);
            uint32_t b3 = nib4(vB.z) | (nib4(vB.w) << 4);
            ow[q] = b0 | (b1 << 8) | (b2 << 16) | (b3 << 24);
        }
        int4v o; o.x = (int)ow[0]; o.y = (int)ow[1]; o.z = (int)ow[2]; o.w = (int)ow[3];
        *(int4v*)(XB + (size_t)u * 1024 + lane * 16) = o;
    } else {                                 // ---- W piece ----
        int v = u - 16384;
        int g = v & 7, kt = (v >> 3) & 63, G = v >> 9;
        int o     = G * 256 + g * 32 + (lane & 31);
        int kbase = kt * 64 + (lane >> 5) * 32;
        const float* src = W + (size_t)kbase * O_DIM + o;
        uint32_t ow[4];
        #pragma unroll
        for (int q = 0; q < 4; ++q) {
            uint32_t x = 0;
            #pragma unroll
            for (int j = 0; j < 8; ++j) {
                float f = src[(size_t)(q * 8 + j) * O_DIM];
                x |= nib4(f) << (4 * j);
            }
            ow[q] = x;
        }
        int4v ov; ov.x = (int)ow[0]; ov.y = (int)ow[1]; ov.z = (int)ow[2]; ov.w = (int)ow[3];
        *(int4v*)(WB + (size_t)v * 1024 + lane * 16) = ov;
    }
}

// ====================== 256x128 fp4 GEMM, BK=128, 3-deep pipeline ===========
#define MFMA4(a, b, c)                                                        \
    __builtin_amdgcn_mfma_scale_f32_32x32x64_f8f6f4(                          \
        (a), (b), (c), 4, 4, 0, 0x7F7F7F7F, 0, 0x7F7F7F7F)

__global__ __launch_bounds__(256, 2) void fp4_gemm_kernel(
        const uint8_t* __restrict__ XB, const uint8_t* __restrict__ WB,
        const float* __restrict__ bias, float* __restrict__ out) {
    __shared__ uint8_t lds[3 * 24576];   // 72 KiB: per buf [A 16KB | B 8KB]

    const int tid  = threadIdx.x;
    const int swzb = (blockIdx.x & 7) * 128 + (blockIdx.x >> 3);  // XCD swizzle
    const int brow = (swzb >> 5) * 256;
    const int bcol = (swzb & 31) * 128;

    const int lane = tid & 63;
    const int wid  = tid >> 6;
    const int wrow = (wid >> 1) * 128;   // 2 M-groups
    const int wcol = (wid & 1) * 64;     // 2 N-groups
    const int l31  = lane & 31;
    const int lh   = lane >> 5;

    const int ag0 = (wrow >> 5) * 1024 + lane * 16;          // A piece base
    const int bg0 = 16384 + (wcol >> 5) * 1024 + lane * 16;  // B piece base

    const uint8_t* Asrc = XB + ((size_t)(brow >> 8) << 19) + tid * 16;
    const uint8_t* Bsrc = WB + ((size_t)(bcol >> 8) << 19)
                             + ((bcol & 255) >> 5) * 1024 + tid * 16;

#define GSTAGE(buf, t)                                                        \
    {                                                                         \
        _Pragma("unroll")                                                     \
        for (int j = 0; j < 4; ++j) {                                         \
            __builtin_amdgcn_global_load_lds(                                 \
                (const __attribute__((address_space(1))) void*)               \
                    (Asrc + (size_t)(t) * 16384 + j * 4096),                  \
                (__attribute__((address_space(3))) void*)                     \
                    (lds + (buf) * 24576 + j * 4096 + tid * 16), 16, 0, 0);   \
        }                                                                     \
        _Pragma("unroll")                                                     \
        for (int h = 0; h < 2; ++h) {                                         \
            __builtin_amdgcn_global_load_lds(                                 \
                (const __attribute__((address_space(1))) void*)               \
                    (Bsrc + (size_t)(t) * 16384 + h * 8192),                  \
                (__attribute__((address_space(3))) void*)                     \
                    (lds + (buf) * 24576 + 16384 + h * 4096 + tid * 16),      \
                16, 0, 0);                                                    \
        }                                                                     \
    }

    // read fragments of k-half h from buffer buf into one named set
#define LOADH(A0, A1, A2, A3, B0, B1, buf, h)                                 \
    {                                                                         \
        const uint8_t* Ap = lds + (buf) * 24576 + (h) * 8192 + ag0;           \
        const uint8_t* Bp = lds + (buf) * 24576 + (h) * 4096 + bg0;           \
        A0 = mk8u(*(const int4v*)(Ap));                                       \
        A1 = mk8u(*(const int4v*)(Ap + 1024));                                \
        A2 = mk8u(*(const int4v*)(Ap + 2048));                                \
        A3 = mk8u(*(const int4v*)(Ap + 3072));                                \
        B0 = mk8u(*(const int4v*)(Bp));                                       \
        B1 = mk8u(*(const int4v*)(Bp + 1024));                                \
    }

#define MFMA8(A0, A1, A2, A3, B0, B1)                                         \
    {                                                                         \
        __builtin_amdgcn_s_setprio(1);                                        \
        c00 = MFMA4(A0, B0, c00);  c01 = MFMA4(A0, B1, c01);                  \
        c10 = MFMA4(A1, B0, c10);  c11 = MFMA4(A1, B1, c11);                  \
        c20 = MFMA4(A2, B0, c20);  c21 = MFMA4(A2, B1, c21);                  \
        c30 = MFMA4(A3, B0, c30);  c31 = MFMA4(A3, B1, c31);                  \
        __builtin_amdgcn_s_setprio(0);                                        \
    }

    // one BK=128 step: wait -> barrier -> stage(t+2) -> 2 half-clusters
#define STEP(bufc, bufs, t, LASTWAIT)                                         \
    {                                                                         \
        if (LASTWAIT) asm volatile("s_waitcnt vmcnt(0)" ::: "memory");        \
        else          asm volatile("s_waitcnt vmcnt(6)" ::: "memory");        \
        __builtin_amdgcn_s_barrier();                                         \
        if ((t) + 2 < 32) GSTAGE(bufs, (t) + 2);                              \
        LOADH(a0, a1, a2, a3, b0, b1, bufc, 0);                               \
        LOADH(na0, na1, na2, na3, nb0, nb1, bufc, 1);                         \
        MFMA8(a0, a1, a2, a3, b0, b1);                                        \
        MFMA8(na0, na1, na2, na3, nb0, nb1);                                  \
    }

    float16v c00 = 0, c01 = 0, c10 = 0, c11 = 0,
             c20 = 0, c21 = 0, c30 = 0, c31 = 0;
    int8v a0, a1, a2, a3, b0, b1;
    int8v na0, na1, na2, na3, nb0, nb1;

    // prologue: stage steps 0,1 (12 loads in flight)
    GSTAGE(0, 0);
    GSTAGE(1, 1);

    // t = 0..29 in 10 statically-indexed triples; tail t = 30 (buf 0), 31 (buf 1)
    for (int i = 0; i < 10; ++i) {
        const int t = 3 * i;
        STEP(0, 2, t,     false);
        STEP(1, 0, t + 1, false);
        STEP(2, 1, t + 2, false);
    }
    STEP(0, 2, 30, false);
    STEP(1, 0, 31, true);
#undef STEP
#undef MFMA8
#undef LOADH
#undef GSTAGE

    // epilogue: C/D map col=lane&31, row=(r&3)+8*(r>>2)+4*(lane>>5)
    float bv0 = bias[bcol + wcol + l31];
    float bv1 = bias[bcol + wcol + 32 + l31];
    const size_t obase = (size_t)(brow + wrow) * O_DIM + bcol + wcol;

#define CWRITE(cm, m, n, bv)                                                  \
    {                                                                         \
        _Pragma("unroll")                                                     \
        for (int r = 0; r < 16; ++r) {                                        \
            int rl = (r & 3) + 8 * (r >> 2) + 4 * lh;                         \
            out[obase + (size_t)((m) * 32 + rl) * O_DIM + (n) * 32 + l31] =   \
                cm[r] + (bv);                                                 \
        }                                                                     \
    }

    CWRITE(c00, 0, 0, bv0); CWRITE(c01, 0, 1, bv1);
    CWRITE(c10, 1, 0, bv0); CWRITE(c11, 1, 1, bv1);
    CWRITE(c20, 2, 0, bv0); CWRITE(c21, 2, 1, bv1);
    CWRITE(c30, 3, 0, bv0); CWRITE(c31, 3, 1, bv1);
#undef CWRITE
}

// ====================== popcount fallback (round-5, proven) =================
__global__ __launch_bounds__(256) void pack_x_kernel(
        const float* __restrict__ X, uint64_t* __restrict__ Xb) {
    int wave = (int)((blockIdx.x * blockDim.x + threadIdx.x) >> 6);
    int lane = threadIdx.x & 63;
    if (wave >= N_ROWS) return;
    const float* xr = X + (size_t)wave * K_DIM;
    uint64_t* xbr = Xb + (size_t)wave * KW;
    #pragma unroll 4
    for (int w = 0; w < KW; ++w) {
        float v = xr[w * 64 + lane];
        unsigned long long m = __ballot(v > 0.0f);
        if (lane == 0) xbr[w] = (uint64_t)m;
    }
}

__global__ __launch_bounds__(256) void pack_w_kernel(
        const float* __restrict__ W, uint64_t* __restrict__ Wb) {
    int oc = blockIdx.x & 15;
    int w  = blockIdx.x >> 4;
    int o  = oc * 256 + threadIdx.x;
    const float* wp = W + (size_t)(w * 64) * O_DIM + o;
    uint64_t word = 0;
    #pragma unroll 8
    for (int p = 0; p < 64; ++p) {
        float v = wp[(size_t)p * O_DIM];
        word |= (uint64_t)(v > 0.0f) << p;
    }
    Wb[(size_t)o * KW + w] = word;
}

__global__ __launch_bounds__(256) void xnor_gemm_kernel(
        const uint8_t* __restrict__ Xb, const uint8_t* __restrict__ Wb,
        const float* __restrict__ bias, float* __restrict__ out) {
    __shared__ uint4 lds4[2048];
    const int tid    = threadIdx.x;
    const int brow   = (blockIdx.x >> 5) * 128;
    const int bcol   = (blockIdx.x & 31) * 128;
    const int tx     = tid & 15;
    const int ty     = tid >> 4;
    const int widx   = tid >> 6;
    const int xbase0 = ty * 64 + (ty & 7);
    const int wbase0 = 1024 + tx * 64 + (tx & 7);
    uint32_t acc[8][8] = {};
    for (int kc = 0; kc < 4; ++kc) {
        __syncthreads();
        #pragma unroll
        for (int i = 0; i < 4; ++i) {
            int idx  = tid + 256 * i;
            int row  = idx >> 3;
            int srcc = (idx & 7) ^ ((idx >> 6) & 7);
            size_t goff = ((size_t)row << 9) + (kc << 7) + (srcc << 4);
            __builtin_amdgcn_global_load_lds(
                (const __attribute__((address_space(1))) void*)
                    (Xb + ((size_t)brow << 9) + goff),
                (__attribute__((address_space(3))) void*)
                    (lds4 + i * 256 + widx * 64), 16, 0, 0);
            __builtin_amdgcn_global_load_lds(
                (const __attribute__((address_space(1))) void*)
                    (Wb + ((size_t)bcol << 9) + goff),
                (__attribute__((address_space(3))) void*)
                    (lds4 + 1024 + i * 256 + widx * 64), 16, 0, 0);
        }
        asm volatile("s_waitcnt vmcnt(0)" ::: "memory");
        __syncthreads();
        for (int kq = 0; kq < 8; ++kq) {
            const uint4* xp = &lds4[xbase0 ^ kq];
            const uint4* wp = &lds4[wbase0 ^ kq];
            uint4 xq[8];
            #pragma unroll
            for (int r = 0; r < 8; ++r) xq[r] = xp[8 * r];
            #pragma unroll
            for (int c = 0; c < 8; ++c) {
                uint4 wv = wp[8 * c];
                #pragma unroll
                for (int r = 0; r < 8; ++r) {
                    uint32_t a = acc[r][c];
                    a = __builtin_popcount(xq[r].x ^ wv.x) + a;
                    a = __builtin_popcount(xq[r].y ^ wv.y) + a;
                    a = __builtin_popcount(xq[r].z ^ wv.z) + a;
                    a = __builtin_popcount(xq[r].w ^ wv.w) + a;
                    acc[r][c] = a;
                }
            }
        }
    }
    float bv[8];
    #pragma unroll
    for (int c = 0; c < 8; ++c) bv[c] = bias[bcol + tx * 8 + c];
    #pragma unroll
    for (int r = 0; r < 8; ++r) {
        float vals[8];
        #pragma unroll
        for (int c = 0; c < 8; ++c)
            vals[c] = (float)(K_DIM - 2 * (int)acc[r][c]) + bv[c];
        float4* op = (float4*)(out + (size_t)(brow + ty * 8 + r) * O_DIM
                               + bcol + tx * 8);
        op[0] = make_float4(vals[0], vals[1], vals[2], vals[3]);
        op[1] = make_float4(vals[4], vals[5], vals[6], vals[7]);
    }
}

// ====================== launcher ============================================
extern "C" void kernel_launch(void* const* d_in, const int* in_sizes, int n_in,
                              void* d_out, int out_size, void* d_ws, size_t ws_size,
                              hipStream_t stream) {
    const float* X    = (const float*)d_in[0];
    const float* W    = (const float*)d_in[1];
    const float* bias = (const float*)d_in[2];
    float* out        = (float*)d_out;

    const size_t XB4 = (size_t)N_ROWS * K_DIM / 2;   // 16 MiB fp4 X
    const size_t WB4 = (size_t)O_DIM * K_DIM / 2;    //  8 MiB fp4 W

    if (ws_size >= XB4 + WB4) {
        uint8_t* XBlk = (uint8_t*)d_ws;
        uint8_t* WBlk = (uint8_t*)d_ws + XB4;

        convert_xw_fp4<<<(16384 + 8192) / 4, 256, 0, stream>>>(X, W, XBlk, WBlk);
        fp4_gemm_kernel<<<(N_ROWS / 256) * (O_DIM / 128), 256, 0, stream>>>(
            XBlk, WBlk, bias, out);
    } else {
        uint64_t* Xb = (uint64_t*)d_ws;
        uint64_t* Wb = (uint64_t*)((uint8_t*)d_ws + (size_t)N_ROWS * KW * 8);
        pack_x_kernel<<<N_ROWS / 4, 256, 0, stream>>>(X, Xb);
        pack_w_kernel<<<16 * 64, 256, 0, stream>>>(W, Wb);
        xnor_gemm_kernel<<<(N_ROWS / 128) * (O_DIM / 128), 256, 0, stream>>>(
            (const uint8_t*)Xb, (const uint8_t*)Wb, bias, out);
    }
}

// Round 24
// 123.767 us; speedup vs baseline: 8.7886x; 1.0194x over previous
//
#include <hip/hip_runtime.h>
#include <stdint.h>

// BinarizeLinear inference: out = sign(X) @ sign(W) + bias
// Round 24: convert MLP push. Profile showed the merged convert is now the
// longest dispatch (82us, 1.2TB/s, latency-bound: only 8 loads in flight
// per X-wave). X-part now processes TWO pieces per wave with all 16 float4
// loads issued before any packing (2x outstanding loads). W-part unchanged
// (already 32 requests/lane in flight). GEMM = round-23 exact (BK=128,
// counted vmcnt(6), 72 KiB LDS, (256,2)). fp4 e2m1 +-1 exact; absmax 0.

#define N_ROWS 8192
#define K_DIM  4096
#define O_DIM  4096
#define KW     64

typedef int   int4v    __attribute__((ext_vector_type(4)));
typedef int   int8v    __attribute__((ext_vector_type(8)));
typedef float float16v __attribute__((ext_vector_type(16)));

// fp4 operand: low 4 regs carry data, high 4 undef (FMT=fp4 ignores them)
__device__ __forceinline__ int8v mk8u(int4v x) {
    return __builtin_shufflevector(x, x, 0, 1, 2, 3, -1, -1, -1, -1);
}

// fp4 e2m1: +1.0 = 0x2, -1.0 = 0xA
__device__ __forceinline__ uint32_t nib4(float f) { return f > 0.0f ? 0x2u : 0xAu; }

// ====================== X and W -> fp4 blocked, ONE kernel ==================
// X: 2048 blocks, 8 pieces/block (2 per wave, 16 loads in flight).
// W: 2048 blocks, 4 pieces/block (1 per wave, 32 dword requests in flight).
__global__ __launch_bounds__(256) void convert_xw_fp4(
        const float* __restrict__ X, const float* __restrict__ W,
        uint8_t* __restrict__ XB, uint8_t* __restrict__ WB) {
    int lane = threadIdx.x & 63;
    int wid  = threadIdx.x >> 6;

    if (blockIdx.x < 2048) {                 // ---- X: two pieces per wave ----
        int u0 = (blockIdx.x * 4 + wid) * 2;
        int g0 = u0 & 7, kt0 = (u0 >> 3) & 63, G0 = u0 >> 9;
        int u1 = u0 + 1;
        int g1 = u1 & 7, kt1 = (u1 >> 3) & 63, G1 = u1 >> 9;

        const float4* s0 = (const float4*)(X
            + (size_t)(G0 * 256 + g0 * 32 + (lane & 31)) * K_DIM
            + kt0 * 64 + (lane >> 5) * 32);
        const float4* s1 = (const float4*)(X
            + (size_t)(G1 * 256 + g1 * 32 + (lane & 31)) * K_DIM
            + kt1 * 64 + (lane >> 5) * 32);

        float4 r0[8], r1[8];
        #pragma unroll
        for (int q = 0; q < 8; ++q) r0[q] = s0[q];
        #pragma unroll
        for (int q = 0; q < 8; ++q) r1[q] = s1[q];

        uint32_t ow0[4], ow1[4];
        #pragma unroll
        for (int q = 0; q < 4; ++q) {
            float4 vA = r0[2 * q], vB = r0[2 * q + 1];
            ow0[q] = nib4(vA.x) | (nib4(vA.y) << 4) | (nib4(vA.z) << 8)
                   | (nib4(vA.w) << 12) | (nib4(vB.x) << 16)
                   | (nib4(vB.y) << 20) | (nib4(vB.z) << 24) | (nib4(vB.w) << 28);
        }
        #pragma unroll
        for (int q = 0; q < 4; ++q) {
            float4 vA = r1[2 * q], vB = r1[2 * q + 1];
            ow1[q] = nib4(vA.x) | (nib4(vA.y) << 4) | (nib4(vA.z) << 8)
                   | (nib4(vA.w) << 12) | (nib4(vB.x) << 16)
                   | (nib4(vB.y) << 20) | (nib4(vB.z) << 24) | (nib4(vB.w) << 28);
        }
        int4v o0; o0.x = (int)ow0[0]; o0.y = (int)ow0[1]; o0.z = (int)ow0[2]; o0.w = (int)ow0[3];
        int4v o1; o1.x = (int)ow1[0]; o1.y = (int)ow1[1]; o1.z = (int)ow1[2]; o1.w = (int)ow1[3];
        *(int4v*)(XB + (size_t)u0 * 1024 + lane * 16) = o0;
        *(int4v*)(XB + (size_t)u1 * 1024 + lane * 16) = o1;
    } else {                                 // ---- W piece (one per wave) ----
        int v = (blockIdx.x - 2048) * 4 + wid;
        int g = v & 7, kt = (v >> 3) & 63, G = v >> 9;
        int o     = G * 256 + g * 32 + (lane & 31);
        int kbase = kt * 64 + (lane >> 5) * 32;
        const float* src = W + (size_t)kbase * O_DIM + o;
        uint32_t ow[4];
        #pragma unroll
        for (int q = 0; q < 4; ++q) {
            uint32_t x = 0;
            #pragma unroll
            for (int j = 0; j < 8; ++j) {
                float f = src[(size_t)(q * 8 + j) * O_DIM];
                x |= nib4(f) << (4 * j);
            }
            ow[q] = x;
        }
        int4v ov; ov.x = (int)ow[0]; ov.y = (int)ow[1]; ov.z = (int)ow[2]; ov.w = (int)ow[3];
        *(int4v*)(WB + (size_t)v * 1024 + lane * 16) = ov;
    }
}

// ====================== 256x128 fp4 GEMM, BK=128, 3-deep pipeline ===========
#define MFMA4(a, b, c)                                                        \
    __builtin_amdgcn_mfma_scale_f32_32x32x64_f8f6f4(                          \
        (a), (b), (c), 4, 4, 0, 0x7F7F7F7F, 0, 0x7F7F7F7F)

__global__ __launch_bounds__(256, 2) void fp4_gemm_kernel(
        const uint8_t* __restrict__ XB, const uint8_t* __restrict__ WB,
        const float* __restrict__ bias, float* __restrict__ out) {
    __shared__ uint8_t lds[3 * 24576];   // 72 KiB: per buf [A 16KB | B 8KB]

    const int tid  = threadIdx.x;
    const int swzb = (blockIdx.x & 7) * 128 + (blockIdx.x >> 3);  // XCD swizzle
    const int brow = (swzb >> 5) * 256;
    const int bcol = (swzb & 31) * 128;

    const int lane = tid & 63;
    const int wid  = tid >> 6;
    const int wrow = (wid >> 1) * 128;   // 2 M-groups
    const int wcol = (wid & 1) * 64;     // 2 N-groups
    const int l31  = lane & 31;
    const int lh   = lane >> 5;

    const int ag0 = (wrow >> 5) * 1024 + lane * 16;          // A piece base
    const int bg0 = 16384 + (wcol >> 5) * 1024 + lane * 16;  // B piece base

    const uint8_t* Asrc = XB + ((size_t)(brow >> 8) << 19) + tid * 16;
    const uint8_t* Bsrc = WB + ((size_t)(bcol >> 8) << 19)
                             + ((bcol & 255) >> 5) * 1024 + tid * 16;

#define GSTAGE(buf, t)                                                        \
    {                                                                         \
        _Pragma("unroll")                                                     \
        for (int j = 0; j < 4; ++j) {                                         \
            __builtin_amdgcn_global_load_lds(                                 \
                (const __attribute__((address_space(1))) void*)               \
                    (Asrc + (size_t)(t) * 16384 + j * 4096),                  \
                (__attribute__((address_space(3))) void*)                     \
                    (lds + (buf) * 24576 + j * 4096 + tid * 16), 16, 0, 0);   \
        }                                                                     \
        _Pragma("unroll")                                                     \
        for (int h = 0; h < 2; ++h) {                                         \
            __builtin_amdgcn_global_load_lds(                                 \
                (const __attribute__((address_space(1))) void*)               \
                    (Bsrc + (size_t)(t) * 16384 + h * 8192),                  \
                (__attribute__((address_space(3))) void*)                     \
                    (lds + (buf) * 24576 + 16384 + h * 4096 + tid * 16),      \
                16, 0, 0);                                                    \
        }                                                                     \
    }

    // read fragments of k-half h from buffer buf into one named set
#define LOADH(A0, A1, A2, A3, B0, B1, buf, h)                                 \
    {                                                                         \
        const uint8_t* Ap = lds + (buf) * 24576 + (h) * 8192 + ag0;           \
        const uint8_t* Bp = lds + (buf) * 24576 + (h) * 4096 + bg0;           \
        A0 = mk8u(*(const int4v*)(Ap));                                       \
        A1 = mk8u(*(const int4v*)(Ap + 1024));                                \
        A2 = mk8u(*(const int4v*)(Ap + 2048));                                \
        A3 = mk8u(*(const int4v*)(Ap + 3072));                                \
        B0 = mk8u(*(const int4v*)(Bp));                                       \
        B1 = mk8u(*(const int4v*)(Bp + 1024));                                \
    }

#define MFMA8(A0, A1, A2, A3, B0, B1)                                         \
    {                                                                         \
        __builtin_amdgcn_s_setprio(1);                                        \
        c00 = MFMA4(A0, B0, c00);  c01 = MFMA4(A0, B1, c01);                  \
        c10 = MFMA4(A1, B0, c10);  c11 = MFMA4(A1, B1, c11);                  \
        c20 = MFMA4(A2, B0, c20);  c21 = MFMA4(A2, B1, c21);                  \
        c30 = MFMA4(A3, B0, c30);  c31 = MFMA4(A3, B1, c31);                  \
        __builtin_amdgcn_s_setprio(0);                                        \
    }

    // one BK=128 step: wait -> barrier -> stage(t+2) -> 2 half-clusters
#define STEP(bufc, bufs, t, LASTWAIT)                                         \
    {                                                                         \
        if (LASTWAIT) asm volatile("s_waitcnt vmcnt(0)" ::: "memory");        \
        else          asm volatile("s_waitcnt vmcnt(6)" ::: "memory");        \
        __builtin_amdgcn_s_barrier();                                         \
        if ((t) + 2 < 32) GSTAGE(bufs, (t) + 2);                              \
        LOADH(a0, a1, a2, a3, b0, b1, bufc, 0);                               \
        LOADH(na0, na1, na2, na3, nb0, nb1, bufc, 1);                         \
        MFMA8(a0, a1, a2, a3, b0, b1);                                        \
        MFMA8(na0, na1, na2, na3, nb0, nb1);                                  \
    }

    float16v c00 = 0, c01 = 0, c10 = 0, c11 = 0,
             c20 = 0, c21 = 0, c30 = 0, c31 = 0;
    int8v a0, a1, a2, a3, b0, b1;
    int8v na0, na1, na2, na3, nb0, nb1;

    // prologue: stage steps 0,1 (12 loads in flight)
    GSTAGE(0, 0);
    GSTAGE(1, 1);

    // t = 0..29 in 10 statically-indexed triples; tail t = 30 (buf 0), 31 (buf 1)
    for (int i = 0; i < 10; ++i) {
        const int t = 3 * i;
        STEP(0, 2, t,     false);
        STEP(1, 0, t + 1, false);
        STEP(2, 1, t + 2, false);
    }
    STEP(0, 2, 30, false);
    STEP(1, 0, 31, true);
#undef STEP
#undef MFMA8
#undef LOADH
#undef GSTAGE

    // epilogue: C/D map col=lane&31, row=(r&3)+8*(r>>2)+4*(lane>>5)
    float bv0 = bias[bcol + wcol + l31];
    float bv1 = bias[bcol + wcol + 32 + l31];
    const size_t obase = (size_t)(brow + wrow) * O_DIM + bcol + wcol;

#define CWRITE(cm, m, n, bv)                                                  \
    {                                                                         \
        _Pragma("unroll")                                                     \
        for (int r = 0; r < 16; ++r) {                                        \
            int rl = (r & 3) + 8 * (r >> 2) + 4 * lh;                         \
            out[obase + (size_t)((m) * 32 + rl) * O_DIM + (n) * 32 + l31] =   \
                cm[r] + (bv);                                                 \
        }                                                                     \
    }

    CWRITE(c00, 0, 0, bv0); CWRITE(c01, 0, 1, bv1);
    CWRITE(c10, 1, 0, bv0); CWRITE(c11, 1, 1, bv1);
    CWRITE(c20, 2, 0, bv0); CWRITE(c21, 2, 1, bv1);
    CWRITE(c30, 3, 0, bv0); CWRITE(c31, 3, 1, bv1);
#undef CWRITE
}

// ====================== popcount fallback (round-5, proven) =================
__global__ __launch_bounds__(256) void pack_x_kernel(
        const float* __restrict__ X, uint64_t* __restrict__ Xb) {
    int wave = (int)((blockIdx.x * blockDim.x + threadIdx.x) >> 6);
    int lane = threadIdx.x & 63;
    if (wave >= N_ROWS) return;
    const float* xr = X + (size_t)wave * K_DIM;
    uint64_t* xbr = Xb + (size_t)wave * KW;
    #pragma unroll 4
    for (int w = 0; w < KW; ++w) {
        float v = xr[w * 64 + lane];
        unsigned long long m = __ballot(v > 0.0f);
        if (lane == 0) xbr[w] = (uint64_t)m;
    }
}

__global__ __launch_bounds__(256) void pack_w_kernel(
        const float* __restrict__ W, uint64_t* __restrict__ Wb) {
    int oc = blockIdx.x & 15;
    int w  = blockIdx.x >> 4;
    int o  = oc * 256 + threadIdx.x;
    const float* wp = W + (size_t)(w * 64) * O_DIM + o;
    uint64_t word = 0;
    #pragma unroll 8
    for (int p = 0; p < 64; ++p) {
        float v = wp[(size_t)p * O_DIM];
        word |= (uint64_t)(v > 0.0f) << p;
    }
    Wb[(size_t)o * KW + w] = word;
}

__global__ __launch_bounds__(256) void xnor_gemm_kernel(
        const uint8_t* __restrict__ Xb, const uint8_t* __restrict__ Wb,
        const float* __restrict__ bias, float* __restrict__ out) {
    __shared__ uint4 lds4[2048];
    const int tid    = threadIdx.x;
    const int brow   = (blockIdx.x >> 5) * 128;
    const int bcol   = (blockIdx.x & 31) * 128;
    const int tx     = tid & 15;
    const int ty     = tid >> 4;
    const int widx   = tid >> 6;
    const int xbase0 = ty * 64 + (ty & 7);
    const int wbase0 = 1024 + tx * 64 + (tx & 7);
    uint32_t acc[8][8] = {};
    for (int kc = 0; kc < 4; ++kc) {
        __syncthreads();
        #pragma unroll
        for (int i = 0; i < 4; ++i) {
            int idx  = tid + 256 * i;
            int row  = idx >> 3;
            int srcc = (idx & 7) ^ ((idx >> 6) & 7);
            size_t goff = ((size_t)row << 9) + (kc << 7) + (srcc << 4);
            __builtin_amdgcn_global_load_lds(
                (const __attribute__((address_space(1))) void*)
                    (Xb + ((size_t)brow << 9) + goff),
                (__attribute__((address_space(3))) void*)
                    (lds4 + i * 256 + widx * 64), 16, 0, 0);
            __builtin_amdgcn_global_load_lds(
                (const __attribute__((address_space(1))) void*)
                    (Wb + ((size_t)bcol << 9) + goff),
                (__attribute__((address_space(3))) void*)
                    (lds4 + 1024 + i * 256 + widx * 64), 16, 0, 0);
        }
        asm volatile("s_waitcnt vmcnt(0)" ::: "memory");
        __syncthreads();
        for (int kq = 0; kq < 8; ++kq) {
            const uint4* xp = &lds4[xbase0 ^ kq];
            const uint4* wp = &lds4[wbase0 ^ kq];
            uint4 xq[8];
            #pragma unroll
            for (int r = 0; r < 8; ++r) xq[r] = xp[8 * r];
            #pragma unroll
            for (int c = 0; c < 8; ++c) {
                uint4 wv = wp[8 * c];
                #pragma unroll
                for (int r = 0; r < 8; ++r) {
                    uint32_t a = acc[r][c];
                    a = __builtin_popcount(xq[r].x ^ wv.x) + a;
                    a = __builtin_popcount(xq[r].y ^ wv.y) + a;
                    a = __builtin_popcount(xq[r].z ^ wv.z) + a;
                    a = __builtin_popcount(xq[r].w ^ wv.w) + a;
                    acc[r][c] = a;
                }
            }
        }
    }
    float bv[8];
    #pragma unroll
    for (int c = 0; c < 8; ++c) bv[c] = bias[bcol + tx * 8 + c];
    #pragma unroll
    for (int r = 0; r < 8; ++r) {
        float vals[8];
        #pragma unroll
        for (int c = 0; c < 8; ++c)
            vals[c] = (float)(K_DIM - 2 * (int)acc[r][c]) + bv[c];
        float4* op = (float4*)(out + (size_t)(brow + ty * 8 + r) * O_DIM
                               + bcol + tx * 8);
        op[0] = make_float4(vals[0], vals[1], vals[2], vals[3]);
        op[1] = make_float4(vals[4], vals[5], vals[6], vals[7]);
    }
}

// ====================== launcher ============================================
extern "C" void kernel_launch(void* const* d_in, const int* in_sizes, int n_in,
                              void* d_out, int out_size, void* d_ws, size_t ws_size,
                              hipStream_t stream) {
    const float* X    = (const float*)d_in[0];
    const float* W    = (const float*)d_in[1];
    const float* bias = (const float*)d_in[2];
    float* out        = (float*)d_out;

    const size_t XB4 = (size_t)N_ROWS * K_DIM / 2;   // 16 MiB fp4 X
    const size_t WB4 = (size_t)O_DIM * K_DIM / 2;    //  8 MiB fp4 W

    if (ws_size >= XB4 + WB4) {
        uint8_t* XBlk = (uint8_t*)d_ws;
        uint8_t* WBlk = (uint8_t*)d_ws + XB4;

        convert_xw_fp4<<<2048 + 2048, 256, 0, stream>>>(X, W, XBlk, WBlk);
        fp4_gemm_kernel<<<(N_ROWS / 256) * (O_DIM / 128), 256, 0, stream>>>(
            XBlk, WBlk, bias, out);
    } else {
        uint64_t* Xb = (uint64_t*)d_ws;
        uint64_t* Wb = (uint64_t*)((uint8_t*)d_ws + (size_t)N_ROWS * KW * 8);
        pack_x_kernel<<<N_ROWS / 4, 256, 0, stream>>>(X, Xb);
        pack_w_kernel<<<16 * 64, 256, 0, stream>>>(W, Wb);
        xnor_gemm_kernel<<<(N_ROWS / 128) * (O_DIM / 128), 256, 0, stream>>>(
            (const uint8_t*)Xb, (const uint8_t*)Wb, bias, out);
    }
}

// Round 25
// 122.665 us; speedup vs baseline: 8.8675x; 1.0090x over previous
//
#include <hip/hip_runtime.h>
#include <stdint.h>

// BinarizeLinear inference: out = sign(X) @ sign(W) + bias
// Round 25: X-convert rebuilt as copy-style transpose-through-LDS. Phase 1:
// 32 streaming iterations, block reads 4KB CONTIGUOUS per instruction
// (m13 pattern), packs 4 floats -> ushort nibbles -> LDS (row pitch 528B).
// Phase 2: one barrier, wave-contiguous 1KB stores in the GEMM's blocked
// layout. W-part and GEMM unchanged (r23/r24, absmax 0 proven).

#define N_ROWS 8192
#define K_DIM  4096
#define O_DIM  4096
#define KW     64

typedef int   int4v    __attribute__((ext_vector_type(4)));
typedef int   int8v    __attribute__((ext_vector_type(8)));
typedef float float16v __attribute__((ext_vector_type(16)));

__device__ __forceinline__ int8v mk8u(int4v x) {
    return __builtin_shufflevector(x, x, 0, 1, 2, 3, -1, -1, -1, -1);
}

// fp4 e2m1: +1.0 = 0x2, -1.0 = 0xA
__device__ __forceinline__ uint32_t nib4(float f) { return f > 0.0f ? 0x2u : 0xAu; }

// ====================== X and W -> fp4 blocked, ONE kernel ==================
// Blocks 0..1023: X tiles (32 rows x 1024 k). Blocks 1024..3071: W (r24 path).
#define XP 528   // LDS row pitch (512 data + 16 pad), 16B-aligned

__global__ __launch_bounds__(256) void convert_xw_fp4(
        const float* __restrict__ X, const float* __restrict__ W,
        uint8_t* __restrict__ XB, uint8_t* __restrict__ WB) {
    __shared__ uint8_t slds[32 * XP];    // 16.5 KiB (X branch only)
    int tid  = threadIdx.x;
    int lane = tid & 63;
    int wid  = tid >> 6;

    if (blockIdx.x < 1024) {             // ---- X: transpose through LDS ----
        int rowgrp = blockIdx.x >> 2;    // 0..255 (32-row group)
        int kq     = blockIdx.x & 3;     // 0..3 (1024-k quarter)
        const float* xbase = X + (size_t)rowgrp * 32 * K_DIM + kq * 1024;

        // phase 1: 32 rows; per iter the block reads 4KB contiguous
        for (int r = 0; r < 32; ++r) {
            float4 v = ((const float4*)(xbase + (size_t)r * K_DIM))[tid];
            uint32_t b0 = nib4(v.x) | (nib4(v.y) << 4);
            uint32_t b1 = nib4(v.z) | (nib4(v.w) << 4);
            *(uint16_t*)(slds + r * XP + tid * 2) = (uint16_t)(b0 | (b1 << 8));
        }
        __syncthreads();

        // phase 2: 16 pieces (kt = kq*16 + p); wave w -> p = w*4 + i.
        // piece slot lane L = khalf*32 + row31 = our lane index directly.
        int row31 = lane & 31, khalf = lane >> 5;
        #pragma unroll
        for (int i = 0; i < 4; ++i) {
            int p  = wid * 4 + i;
            int kt = kq * 16 + p;
            uint4 val = *(const uint4*)(slds + row31 * XP + p * 32 + khalf * 16);
            size_t base = ((size_t)(rowgrp >> 3) << 19) + (size_t)kt * 8192
                        + (size_t)(rowgrp & 7) * 1024;
            *(uint4*)(XB + base + lane * 16) = val;
        }
    } else {                             // ---- W piece (one per wave) ----
        int v = (int)(blockIdx.x - 1024) * 4 + wid;
        int g = v & 7, kt = (v >> 3) & 63, G = v >> 9;
        int o     = G * 256 + g * 32 + (lane & 31);
        int kbase = kt * 64 + (lane >> 5) * 32;
        const float* src = W + (size_t)kbase * O_DIM + o;
        uint32_t ow[4];
        #pragma unroll
        for (int q = 0; q < 4; ++q) {
            uint32_t x = 0;
            #pragma unroll
            for (int j = 0; j < 8; ++j) {
                float f = src[(size_t)(q * 8 + j) * O_DIM];
                x |= nib4(f) << (4 * j);
            }
            ow[q] = x;
        }
        int4v ov; ov.x = (int)ow[0]; ov.y = (int)ow[1]; ov.z = (int)ow[2]; ov.w = (int)ow[3];
        *(int4v*)(WB + (size_t)v * 1024 + lane * 16) = ov;
    }
}

// ====================== 256x128 fp4 GEMM, BK=128, 3-deep pipeline ===========
#define MFMA4(a, b, c)                                                        \
    __builtin_amdgcn_mfma_scale_f32_32x32x64_f8f6f4(                          \
        (a), (b), (c), 4, 4, 0, 0x7F7F7F7F, 0, 0x7F7F7F7F)

__global__ __launch_bounds__(256, 2) void fp4_gemm_kernel(
        const uint8_t* __restrict__ XB, const uint8_t* __restrict__ WB,
        const float* __restrict__ bias, float* __restrict__ out) {
    __shared__ uint8_t lds[3 * 24576];   // 72 KiB: per buf [A 16KB | B 8KB]

    const int tid  = threadIdx.x;
    const int swzb = (blockIdx.x & 7) * 128 + (blockIdx.x >> 3);  // XCD swizzle
    const int brow = (swzb >> 5) * 256;
    const int bcol = (swzb & 31) * 128;

    const int lane = tid & 63;
    const int wid  = tid >> 6;
    const int wrow = (wid >> 1) * 128;   // 2 M-groups
    const int wcol = (wid & 1) * 64;     // 2 N-groups
    const int l31  = lane & 31;
    const int lh   = lane >> 5;

    const int ag0 = (wrow >> 5) * 1024 + lane * 16;          // A piece base
    const int bg0 = 16384 + (wcol >> 5) * 1024 + lane * 16;  // B piece base

    const uint8_t* Asrc = XB + ((size_t)(brow >> 8) << 19) + tid * 16;
    const uint8_t* Bsrc = WB + ((size_t)(bcol >> 8) << 19)
                             + ((bcol & 255) >> 5) * 1024 + tid * 16;

#define GSTAGE(buf, t)                                                        \
    {                                                                         \
        _Pragma("unroll")                                                     \
        for (int j = 0; j < 4; ++j) {                                         \
            __builtin_amdgcn_global_load_lds(                                 \
                (const __attribute__((address_space(1))) void*)               \
                    (Asrc + (size_t)(t) * 16384 + j * 4096),                  \
                (__attribute__((address_space(3))) void*)                     \
                    (lds + (buf) * 24576 + j * 4096 + tid * 16), 16, 0, 0);   \
        }                                                                     \
        _Pragma("unroll")                                                     \
        for (int h = 0; h < 2; ++h) {                                         \
            __builtin_amdgcn_global_load_lds(                                 \
                (const __attribute__((address_space(1))) void*)               \
                    (Bsrc + (size_t)(t) * 16384 + h * 8192),                  \
                (__attribute__((address_space(3))) void*)                     \
                    (lds + (buf) * 24576 + 16384 + h * 4096 + tid * 16),      \
                16, 0, 0);                                                    \
        }                                                                     \
    }

#define LOADH(A0, A1, A2, A3, B0, B1, buf, h)                                 \
    {                                                                         \
        const uint8_t* Ap = lds + (buf) * 24576 + (h) * 8192 + ag0;           \
        const uint8_t* Bp = lds + (buf) * 24576 + (h) * 4096 + bg0;           \
        A0 = mk8u(*(const int4v*)(Ap));                                       \
        A1 = mk8u(*(const int4v*)(Ap + 1024));                                \
        A2 = mk8u(*(const int4v*)(Ap + 2048));                                \
        A3 = mk8u(*(const int4v*)(Ap + 3072));                                \
        B0 = mk8u(*(const int4v*)(Bp));                                       \
        B1 = mk8u(*(const int4v*)(Bp + 1024));                                \
    }

#define MFMA8(A0, A1, A2, A3, B0, B1)                                         \
    {                                                                         \
        __builtin_amdgcn_s_setprio(1);                                        \
        c00 = MFMA4(A0, B0, c00);  c01 = MFMA4(A0, B1, c01);                  \
        c10 = MFMA4(A1, B0, c10);  c11 = MFMA4(A1, B1, c11);                  \
        c20 = MFMA4(A2, B0, c20);  c21 = MFMA4(A2, B1, c21);                  \
        c30 = MFMA4(A3, B0, c30);  c31 = MFMA4(A3, B1, c31);                  \
        __builtin_amdgcn_s_setprio(0);                                        \
    }

#define STEP(bufc, bufs, t, LASTWAIT)                                         \
    {                                                                         \
        if (LASTWAIT) asm volatile("s_waitcnt vmcnt(0)" ::: "memory");        \
        else          asm volatile("s_waitcnt vmcnt(6)" ::: "memory");        \
        __builtin_amdgcn_s_barrier();                                         \
        if ((t) + 2 < 32) GSTAGE(bufs, (t) + 2);                              \
        LOADH(a0, a1, a2, a3, b0, b1, bufc, 0);                               \
        LOADH(na0, na1, na2, na3, nb0, nb1, bufc, 1);                         \
        MFMA8(a0, a1, a2, a3, b0, b1);                                        \
        MFMA8(na0, na1, na2, na3, nb0, nb1);                                  \
    }

    float16v c00 = 0, c01 = 0, c10 = 0, c11 = 0,
             c20 = 0, c21 = 0, c30 = 0, c31 = 0;
    int8v a0, a1, a2, a3, b0, b1;
    int8v na0, na1, na2, na3, nb0, nb1;

    GSTAGE(0, 0);
    GSTAGE(1, 1);

    for (int i = 0; i < 10; ++i) {
        const int t = 3 * i;
        STEP(0, 2, t,     false);
        STEP(1, 0, t + 1, false);
        STEP(2, 1, t + 2, false);
    }
    STEP(0, 2, 30, false);
    STEP(1, 0, 31, true);
#undef STEP
#undef MFMA8
#undef LOADH
#undef GSTAGE

    float bv0 = bias[bcol + wcol + l31];
    float bv1 = bias[bcol + wcol + 32 + l31];
    const size_t obase = (size_t)(brow + wrow) * O_DIM + bcol + wcol;

#define CWRITE(cm, m, n, bv)                                                  \
    {                                                                         \
        _Pragma("unroll")                                                     \
        for (int r = 0; r < 16; ++r) {                                        \
            int rl = (r & 3) + 8 * (r >> 2) + 4 * lh;                         \
            out[obase + (size_t)((m) * 32 + rl) * O_DIM + (n) * 32 + l31] =   \
                cm[r] + (bv);                                                 \
        }                                                                     \
    }

    CWRITE(c00, 0, 0, bv0); CWRITE(c01, 0, 1, bv1);
    CWRITE(c10, 1, 0, bv0); CWRITE(c11, 1, 1, bv1);
    CWRITE(c20, 2, 0, bv0); CWRITE(c21, 2, 1, bv1);
    CWRITE(c30, 3, 0, bv0); CWRITE(c31, 3, 1, bv1);
#undef CWRITE
}

// ====================== popcount fallback (round-5, proven) =================
__global__ __launch_bounds__(256) void pack_x_kernel(
        const float* __restrict__ X, uint64_t* __restrict__ Xb) {
    int wave = (int)((blockIdx.x * blockDim.x + threadIdx.x) >> 6);
    int lane = threadIdx.x & 63;
    if (wave >= N_ROWS) return;
    const float* xr = X + (size_t)wave * K_DIM;
    uint64_t* xbr = Xb + (size_t)wave * KW;
    #pragma unroll 4
    for (int w = 0; w < KW; ++w) {
        float v = xr[w * 64 + lane];
        unsigned long long m = __ballot(v > 0.0f);
        if (lane == 0) xbr[w] = (uint64_t)m;
    }
}

__global__ __launch_bounds__(256) void pack_w_kernel(
        const float* __restrict__ W, uint64_t* __restrict__ Wb) {
    int oc = blockIdx.x & 15;
    int w  = blockIdx.x >> 4;
    int o  = oc * 256 + threadIdx.x;
    const float* wp = W + (size_t)(w * 64) * O_DIM + o;
    uint64_t word = 0;
    #pragma unroll 8
    for (int p = 0; p < 64; ++p) {
        float v = wp[(size_t)p * O_DIM];
        word |= (uint64_t)(v > 0.0f) << p;
    }
    Wb[(size_t)o * KW + w] = word;
}

__global__ __launch_bounds__(256) void xnor_gemm_kernel(
        const uint8_t* __restrict__ Xb, const uint8_t* __restrict__ Wb,
        const float* __restrict__ bias, float* __restrict__ out) {
    __shared__ uint4 lds4[2048];
    const int tid    = threadIdx.x;
    const int brow   = (blockIdx.x >> 5) * 128;
    const int bcol   = (blockIdx.x & 31) * 128;
    const int tx     = tid & 15;
    const int ty     = tid >> 4;
    const int widx   = tid >> 6;
    const int xbase0 = ty * 64 + (ty & 7);
    const int wbase0 = 1024 + tx * 64 + (tx & 7);
    uint32_t acc[8][8] = {};
    for (int kc = 0; kc < 4; ++kc) {
        __syncthreads();
        #pragma unroll
        for (int i = 0; i < 4; ++i) {
            int idx  = tid + 256 * i;
            int row  = idx >> 3;
            int srcc = (idx & 7) ^ ((idx >> 6) & 7);
            size_t goff = ((size_t)row << 9) + (kc << 7) + (srcc << 4);
            __builtin_amdgcn_global_load_lds(
                (const __attribute__((address_space(1))) void*)
                    (Xb + ((size_t)brow << 9) + goff),
                (__attribute__((address_space(3))) void*)
                    (lds4 + i * 256 + widx * 64), 16, 0, 0);
            __builtin_amdgcn_global_load_lds(
                (const __attribute__((address_space(1))) void*)
                    (Wb + ((size_t)bcol << 9) + goff),
                (__attribute__((address_space(3))) void*)
                    (lds4 + 1024 + i * 256 + widx * 64), 16, 0, 0);
        }
        asm volatile("s_waitcnt vmcnt(0)" ::: "memory");
        __syncthreads();
        for (int kq = 0; kq < 8; ++kq) {
            const uint4* xp = &lds4[xbase0 ^ kq];
            const uint4* wp = &lds4[wbase0 ^ kq];
            uint4 xq[8];
            #pragma unroll
            for (int r = 0; r < 8; ++r) xq[r] = xp[8 * r];
            #pragma unroll
            for (int c = 0; c < 8; ++c) {
                uint4 wv = wp[8 * c];
                #pragma unroll
                for (int r = 0; r < 8; ++r) {
                    uint32_t a = acc[r][c];
                    a = __builtin_popcount(xq[r].x ^ wv.x) + a;
                    a = __builtin_popcount(xq[r].y ^ wv.y) + a;
                    a = __builtin_popcount(xq[r].z ^ wv.z) + a;
                    a = __builtin_popcount(xq[r].w ^ wv.w) + a;
                    acc[r][c] = a;
                }
            }
        }
    }
    float bv[8];
    #pragma unroll
    for (int c = 0; c < 8; ++c) bv[c] = bias[bcol + tx * 8 + c];
    #pragma unroll
    for (int r = 0; r < 8; ++r) {
        float vals[8];
        #pragma unroll
        for (int c = 0; c < 8; ++c)
            vals[c] = (float)(K_DIM - 2 * (int)acc[r][c]) + bv[c];
        float4* op = (float4*)(out + (size_t)(brow + ty * 8 + r) * O_DIM
                               + bcol + tx * 8);
        op[0] = make_float4(vals[0], vals[1], vals[2], vals[3]);
        op[1] = make_float4(vals[4], vals[5], vals[6], vals[7]);
    }
}

// ====================== launcher ============================================
extern "C" void kernel_launch(void* const* d_in, const int* in_sizes, int n_in,
                              void* d_out, int out_size, void* d_ws, size_t ws_size,
                              hipStream_t stream) {
    const float* X    = (const float*)d_in[0];
    const float* W    = (const float*)d_in[1];
    const float* bias = (const float*)d_in[2];
    float* out        = (float*)d_out;

    const size_t XB4 = (size_t)N_ROWS * K_DIM / 2;   // 16 MiB fp4 X
    const size_t WB4 = (size_t)O_DIM * K_DIM / 2;    //  8 MiB fp4 W

    if (ws_size >= XB4 + WB4) {
        uint8_t* XBlk = (uint8_t*)d_ws;
        uint8_t* WBlk = (uint8_t*)d_ws + XB4;

        convert_xw_fp4<<<1024 + 2048, 256, 0, stream>>>(X, W, XBlk, WBlk);
        fp4_gemm_kernel<<<(N_ROWS / 256) * (O_DIM / 128), 256, 0, stream>>>(
            XBlk, WBlk, bias, out);
    } else {
        uint64_t* Xb = (uint64_t*)d_ws;
        uint64_t* Wb = (uint64_t*)((uint8_t*)d_ws + (size_t)N_ROWS * KW * 8);
        pack_x_kernel<<<N_ROWS / 4, 256, 0, stream>>>(X, Xb);
        pack_w_kernel<<<16 * 64, 256, 0, stream>>>(W, Wb);
        xnor_gemm_kernel<<<(N_ROWS / 128) * (O_DIM / 128), 256, 0, stream>>>(
            (const uint8_t*)Xb, (const uint8_t*)Wb, bias, out);
    }
}

// Round 26
// 118.004 us; speedup vs baseline: 9.2177x; 1.0395x over previous
//
#include <hip/hip_runtime.h>
#include <stdint.h>

// BinarizeLinear inference: out = sign(X) @ sign(W) + bias
// Round 26: convert rebuilt around global_load_lds (the only mechanism that
// has reliably kept loads in flight all session -- zero reg pressure, so the
// compiler can't sink them). Phase 1: stage raw fp32 tiles into LDS with
// 16 gloads/wave outstanding, fully contiguous sources. Phase 2: pack
// nibbles from LDS, wave-contiguous 1KB stores in the GEMM's blocked
// layout. GEMM = r23 exact (absmax 0 proven three times).

#define N_ROWS 8192
#define K_DIM  4096
#define O_DIM  4096
#define KW     64

typedef int   int4v    __attribute__((ext_vector_type(4)));
typedef int   int8v    __attribute__((ext_vector_type(8)));
typedef float float16v __attribute__((ext_vector_type(16)));

__device__ __forceinline__ int8v mk8u(int4v x) {
    return __builtin_shufflevector(x, x, 0, 1, 2, 3, -1, -1, -1, -1);
}

// fp4 e2m1: +1.0 = 0x2, -1.0 = 0xA
__device__ __forceinline__ uint32_t nib4(float f) { return f > 0.0f ? 0x2u : 0xAu; }

// pack 8 consecutive floats (k-ascending) into one u32 of nibbles
__device__ __forceinline__ uint32_t pack8(const float* f) {
    uint32_t v = 0;
    #pragma unroll
    for (int j = 0; j < 8; ++j) v |= nib4(f[j]) << (4 * j);
    return v;
}

// ====================== X and W -> fp4 blocked, ONE kernel ==================
// X blocks [0,2048): 32 rows x 512 k, LDS pitch 2064 (pad 16).
// W blocks [2048,3072): 64 k-rows x 256 o, LDS linear 1KB rows.
#define XPITCH 2064

__global__ __launch_bounds__(256) void convert_xw_fp4(
        const float* __restrict__ X, const float* __restrict__ W,
        uint8_t* __restrict__ XB, uint8_t* __restrict__ WB) {
    __shared__ uint8_t slds[32 * XPITCH];   // 66048 B (>= 64KB W usage)
    const int tid  = threadIdx.x;
    const int lane = tid & 63;
    const int wid  = tid >> 6;

    if (blockIdx.x < 2048) {
        // ---------------- X: rows r0..r0+31, k in [kq*512, kq*512+512) -----
        const int r0 = (blockIdx.x >> 3) * 32;
        const int kq = blockIdx.x & 7;
        const float* xs = X + (size_t)r0 * K_DIM + kq * 512;

        // phase 1: 16 gload_lds per wave, all independent & in flight
        #pragma unroll
        for (int i = 0; i < 16; ++i) {
            int p    = wid * 16 + i;        // 0..63
            int row  = p >> 1;
            int half = p & 1;
            __builtin_amdgcn_global_load_lds(
                (const __attribute__((address_space(1))) void*)
                    (xs + (size_t)row * K_DIM + half * 256 + lane * 4),
                (__attribute__((address_space(3))) void*)
                    (slds + row * XPITCH + half * 1024 + lane * 16),
                16, 0, 0);
        }
        asm volatile("s_waitcnt vmcnt(0)" ::: "memory");
        __syncthreads();

        // phase 2: 8 pieces (kt_local 0..7), 2 per wave
        const int row31 = lane & 31;
        const int khalf = lane >> 5;
        const int G = r0 >> 8, g = (r0 >> 5) & 7;
        #pragma unroll
        for (int i = 0; i < 2; ++i) {
            int ktl = wid * 2 + i;          // 0..7
            const float* src = (const float*)(slds + row31 * XPITCH
                                              + (ktl * 64 + khalf * 32) * 4);
            float fv[32];
            #pragma unroll
            for (int q = 0; q < 8; ++q)
                *(float4*)(fv + 4 * q) = ((const float4*)src)[q];
            uint32_t ow0 = pack8(fv), ow1 = pack8(fv + 8),
                     ow2 = pack8(fv + 16), ow3 = pack8(fv + 24);
            int4v o; o.x = (int)ow0; o.y = (int)ow1; o.z = (int)ow2; o.w = (int)ow3;
            size_t base = ((size_t)G << 19) + (size_t)(kq * 8 + ktl) * 8192
                        + (size_t)g * 1024;
            *(int4v*)(XB + base + lane * 16) = o;
        }
    } else {
        // ---------------- W: k in [k0,k0+64), o in [o0,o0+256) -------------
        const int wb = (int)blockIdx.x - 2048;   // 0..1023
        const int k0 = (wb >> 4) * 64;
        const int o0 = (wb & 15) * 256;
        const float* ws = W + (size_t)k0 * O_DIM + o0;

        // phase 1: 16 gload_lds per wave (one 1KB k-row each)
        #pragma unroll
        for (int i = 0; i < 16; ++i) {
            int row = wid * 16 + i;         // 0..63
            __builtin_amdgcn_global_load_lds(
                (const __attribute__((address_space(1))) void*)
                    (ws + (size_t)row * O_DIM + lane * 4),
                (__attribute__((address_space(3))) void*)
                    (slds + row * 1024 + lane * 16),
                16, 0, 0);
        }
        asm volatile("s_waitcnt vmcnt(0)" ::: "memory");
        __syncthreads();

        // phase 2: 8 pieces (g 0..7), 2 per wave
        const int o31   = lane & 31;
        const int khalf = lane >> 5;
        const int G = o0 >> 8, kt = k0 >> 6;
        #pragma unroll
        for (int i = 0; i < 2; ++i) {
            int g = wid * 2 + i;            // 0..7
            const uint8_t* col = slds + (khalf * 32) * 1024 + (g * 32 + o31) * 4;
            uint32_t ow[4];
            #pragma unroll
            for (int q = 0; q < 4; ++q) {
                uint32_t v = 0;
                #pragma unroll
                for (int j = 0; j < 8; ++j) {
                    float f = *(const float*)(col + (q * 8 + j) * 1024);
                    v |= nib4(f) << (4 * j);
                }
                ow[q] = v;
            }
            int4v o; o.x = (int)ow[0]; o.y = (int)ow[1]; o.z = (int)ow[2]; o.w = (int)ow[3];
            size_t base = ((size_t)G << 19) + (size_t)kt * 8192 + (size_t)g * 1024;
            *(int4v*)(WB + base + lane * 16) = o;
        }
    }
}

// ====================== 256x128 fp4 GEMM, BK=128, 3-deep pipeline ===========
#define MFMA4(a, b, c)                                                        \
    __builtin_amdgcn_mfma_scale_f32_32x32x64_f8f6f4(                          \
        (a), (b), (c), 4, 4, 0, 0x7F7F7F7F, 0, 0x7F7F7F7F)

__global__ __launch_bounds__(256, 2) void fp4_gemm_kernel(
        const uint8_t* __restrict__ XB, const uint8_t* __restrict__ WB,
        const float* __restrict__ bias, float* __restrict__ out) {
    __shared__ uint8_t lds[3 * 24576];   // 72 KiB: per buf [A 16KB | B 8KB]

    const int tid  = threadIdx.x;
    const int swzb = (blockIdx.x & 7) * 128 + (blockIdx.x >> 3);  // XCD swizzle
    const int brow = (swzb >> 5) * 256;
    const int bcol = (swzb & 31) * 128;

    const int lane = tid & 63;
    const int wid  = tid >> 6;
    const int wrow = (wid >> 1) * 128;   // 2 M-groups
    const int wcol = (wid & 1) * 64;     // 2 N-groups
    const int l31  = lane & 31;
    const int lh   = lane >> 5;

    const int ag0 = (wrow >> 5) * 1024 + lane * 16;          // A piece base
    const int bg0 = 16384 + (wcol >> 5) * 1024 + lane * 16;  // B piece base

    const uint8_t* Asrc = XB + ((size_t)(brow >> 8) << 19) + tid * 16;
    const uint8_t* Bsrc = WB + ((size_t)(bcol >> 8) << 19)
                             + ((bcol & 255) >> 5) * 1024 + tid * 16;

#define GSTAGE(buf, t)                                                        \
    {                                                                         \
        _Pragma("unroll")                                                     \
        for (int j = 0; j < 4; ++j) {                                         \
            __builtin_amdgcn_global_load_lds(                                 \
                (const __attribute__((address_space(1))) void*)               \
                    (Asrc + (size_t)(t) * 16384 + j * 4096),                  \
                (__attribute__((address_space(3))) void*)                     \
                    (lds + (buf) * 24576 + j * 4096 + tid * 16), 16, 0, 0);   \
        }                                                                     \
        _Pragma("unroll")                                                     \
        for (int h = 0; h < 2; ++h) {                                         \
            __builtin_amdgcn_global_load_lds(                                 \
                (const __attribute__((address_space(1))) void*)               \
                    (Bsrc + (size_t)(t) * 16384 + h * 8192),                  \
                (__attribute__((address_space(3))) void*)                     \
                    (lds + (buf) * 24576 + 16384 + h * 4096 + tid * 16),      \
                16, 0, 0);                                                    \
        }                                                                     \
    }

#define LOADH(A0, A1, A2, A3, B0, B1, buf, h)                                 \
    {                                                                         \
        const uint8_t* Ap = lds + (buf) * 24576 + (h) * 8192 + ag0;           \
        const uint8_t* Bp = lds + (buf) * 24576 + (h) * 4096 + bg0;           \
        A0 = mk8u(*(const int4v*)(Ap));                                       \
        A1 = mk8u(*(const int4v*)(Ap + 1024));                                \
        A2 = mk8u(*(const int4v*)(Ap + 2048));                                \
        A3 = mk8u(*(const int4v*)(Ap + 3072));                                \
        B0 = mk8u(*(const int4v*)(Bp));                                       \
        B1 = mk8u(*(const int4v*)(Bp + 1024));                                \
    }

#define MFMA8(A0, A1, A2, A3, B0, B1)                                         \
    {                                                                         \
        __builtin_amdgcn_s_setprio(1);                                        \
        c00 = MFMA4(A0, B0, c00);  c01 = MFMA4(A0, B1, c01);                  \
        c10 = MFMA4(A1, B0, c10);  c11 = MFMA4(A1, B1, c11);                  \
        c20 = MFMA4(A2, B0, c20);  c21 = MFMA4(A2, B1, c21);                  \
        c30 = MFMA4(A3, B0, c30);  c31 = MFMA4(A3, B1, c31);                  \
        __builtin_amdgcn_s_setprio(0);                                        \
    }

#define STEP(bufc, bufs, t, LASTWAIT)                                         \
    {                                                                         \
        if (LASTWAIT) asm volatile("s_waitcnt vmcnt(0)" ::: "memory");        \
        else          asm volatile("s_waitcnt vmcnt(6)" ::: "memory");        \
        __builtin_amdgcn_s_barrier();                                         \
        if ((t) + 2 < 32) GSTAGE(bufs, (t) + 2);                              \
        LOADH(a0, a1, a2, a3, b0, b1, bufc, 0);                               \
        LOADH(na0, na1, na2, na3, nb0, nb1, bufc, 1);                         \
        MFMA8(a0, a1, a2, a3, b0, b1);                                        \
        MFMA8(na0, na1, na2, na3, nb0, nb1);                                  \
    }

    float16v c00 = 0, c01 = 0, c10 = 0, c11 = 0,
             c20 = 0, c21 = 0, c30 = 0, c31 = 0;
    int8v a0, a1, a2, a3, b0, b1;
    int8v na0, na1, na2, na3, nb0, nb1;

    GSTAGE(0, 0);
    GSTAGE(1, 1);

    for (int i = 0; i < 10; ++i) {
        const int t = 3 * i;
        STEP(0, 2, t,     false);
        STEP(1, 0, t + 1, false);
        STEP(2, 1, t + 2, false);
    }
    STEP(0, 2, 30, false);
    STEP(1, 0, 31, true);
#undef STEP
#undef MFMA8
#undef LOADH
#undef GSTAGE

    float bv0 = bias[bcol + wcol + l31];
    float bv1 = bias[bcol + wcol + 32 + l31];
    const size_t obase = (size_t)(brow + wrow) * O_DIM + bcol + wcol;

#define CWRITE(cm, m, n, bv)                                                  \
    {                                                                         \
        _Pragma("unroll")                                                     \
        for (int r = 0; r < 16; ++r) {                                        \
            int rl = (r & 3) + 8 * (r >> 2) + 4 * lh;                         \
            out[obase + (size_t)((m) * 32 + rl) * O_DIM + (n) * 32 + l31] =   \
                cm[r] + (bv);                                                 \
        }                                                                     \
    }

    CWRITE(c00, 0, 0, bv0); CWRITE(c01, 0, 1, bv1);
    CWRITE(c10, 1, 0, bv0); CWRITE(c11, 1, 1, bv1);
    CWRITE(c20, 2, 0, bv0); CWRITE(c21, 2, 1, bv1);
    CWRITE(c30, 3, 0, bv0); CWRITE(c31, 3, 1, bv1);
#undef CWRITE
}

// ====================== popcount fallback (round-5, proven) =================
__global__ __launch_bounds__(256) void pack_x_kernel(
        const float* __restrict__ X, uint64_t* __restrict__ Xb) {
    int wave = (int)((blockIdx.x * blockDim.x + threadIdx.x) >> 6);
    int lane = threadIdx.x & 63;
    if (wave >= N_ROWS) return;
    const float* xr = X + (size_t)wave * K_DIM;
    uint64_t* xbr = Xb + (size_t)wave * KW;
    #pragma unroll 4
    for (int w = 0; w < KW; ++w) {
        float v = xr[w * 64 + lane];
        unsigned long long m = __ballot(v > 0.0f);
        if (lane == 0) xbr[w] = (uint64_t)m;
    }
}

__global__ __launch_bounds__(256) void pack_w_kernel(
        const float* __restrict__ W, uint64_t* __restrict__ Wb) {
    int oc = blockIdx.x & 15;
    int w  = blockIdx.x >> 4;
    int o  = oc * 256 + threadIdx.x;
    const float* wp = W + (size_t)(w * 64) * O_DIM + o;
    uint64_t word = 0;
    #pragma unroll 8
    for (int p = 0; p < 64; ++p) {
        float v = wp[(size_t)p * O_DIM];
        word |= (uint64_t)(v > 0.0f) << p;
    }
    Wb[(size_t)o * KW + w] = word;
}

__global__ __launch_bounds__(256) void xnor_gemm_kernel(
        const uint8_t* __restrict__ Xb, const uint8_t* __restrict__ Wb,
        const float* __restrict__ bias, float* __restrict__ out) {
    __shared__ uint4 lds4[2048];
    const int tid    = threadIdx.x;
    const int brow   = (blockIdx.x >> 5) * 128;
    const int bcol   = (blockIdx.x & 31) * 128;
    const int tx     = tid & 15;
    const int ty     = tid >> 4;
    const int widx   = tid >> 6;
    const int xbase0 = ty * 64 + (ty & 7);
    const int wbase0 = 1024 + tx * 64 + (tx & 7);
    uint32_t acc[8][8] = {};
    for (int kc = 0; kc < 4; ++kc) {
        __syncthreads();
        #pragma unroll
        for (int i = 0; i < 4; ++i) {
            int idx  = tid + 256 * i;
            int row  = idx >> 3;
            int srcc = (idx & 7) ^ ((idx >> 6) & 7);
            size_t goff = ((size_t)row << 9) + (kc << 7) + (srcc << 4);
            __builtin_amdgcn_global_load_lds(
                (const __attribute__((address_space(1))) void*)
                    (Xb + ((size_t)brow << 9) + goff),
                (__attribute__((address_space(3))) void*)
                    (lds4 + i * 256 + widx * 64), 16, 0, 0);
            __builtin_amdgcn_global_load_lds(
                (const __attribute__((address_space(1))) void*)
                    (Wb + ((size_t)bcol << 9) + goff),
                (__attribute__((address_space(3))) void*)
                    (lds4 + 1024 + i * 256 + widx * 64), 16, 0, 0);
        }
        asm volatile("s_waitcnt vmcnt(0)" ::: "memory");
        __syncthreads();
        for (int kq = 0; kq < 8; ++kq) {
            const uint4* xp = &lds4[xbase0 ^ kq];
            const uint4* wp = &lds4[wbase0 ^ kq];
            uint4 xq[8];
            #pragma unroll
            for (int r = 0; r < 8; ++r) xq[r] = xp[8 * r];
            #pragma unroll
            for (int c = 0; c < 8; ++c) {
                uint4 wv = wp[8 * c];
                #pragma unroll
                for (int r = 0; r < 8; ++r) {
                    uint32_t a = acc[r][c];
                    a = __builtin_popcount(xq[r].x ^ wv.x) + a;
                    a = __builtin_popcount(xq[r].y ^ wv.y) + a;
                    a = __builtin_popcount(xq[r].z ^ wv.z) + a;
                    a = __builtin_popcount(xq[r].w ^ wv.w) + a;
                    acc[r][c] = a;
                }
            }
        }
    }
    float bv[8];
    #pragma unroll
    for (int c = 0; c < 8; ++c) bv[c] = bias[bcol + tx * 8 + c];
    #pragma unroll
    for (int r = 0; r < 8; ++r) {
        float vals[8];
        #pragma unroll
        for (int c = 0; c < 8; ++c)
            vals[c] = (float)(K_DIM - 2 * (int)acc[r][c]) + bv[c];
        float4* op = (float4*)(out + (size_t)(brow + ty * 8 + r) * O_DIM
                               + bcol + tx * 8);
        op[0] = make_float4(vals[0], vals[1], vals[2], vals[3]);
        op[1] = make_float4(vals[4], vals[5], vals[6], vals[7]);
    }
}

// ====================== launcher ============================================
extern "C" void kernel_launch(void* const* d_in, const int* in_sizes, int n_in,
                              void* d_out, int out_size, void* d_ws, size_t ws_size,
                              hipStream_t stream) {
    const float* X    = (const float*)d_in[0];
    const float* W    = (const float*)d_in[1];
    const float* bias = (const float*)d_in[2];
    float* out        = (float*)d_out;

    const size_t XB4 = (size_t)N_ROWS * K_DIM / 2;   // 16 MiB fp4 X
    const size_t WB4 = (size_t)O_DIM * K_DIM / 2;    //  8 MiB fp4 W

    if (ws_size >= XB4 + WB4) {
        uint8_t* XBlk = (uint8_t*)d_ws;
        uint8_t* WBlk = (uint8_t*)d_ws + XB4;

        convert_xw_fp4<<<2048 + 1024, 256, 0, stream>>>(X, W, XBlk, WBlk);
        fp4_gemm_kernel<<<(N_ROWS / 256) * (O_DIM / 128), 256, 0, stream>>>(
            XBlk, WBlk, bias, out);
    } else {
        uint64_t* Xb = (uint64_t*)d_ws;
        uint64_t* Wb = (uint64_t*)((uint8_t*)d_ws + (size_t)N_ROWS * KW * 8);
        pack_x_kernel<<<N_ROWS / 4, 256, 0, stream>>>(X, Xb);
        pack_w_kernel<<<16 * 64, 256, 0, stream>>>(W, Wb);
        xnor_gemm_kernel<<<(N_ROWS / 128) * (O_DIM / 128), 256, 0, stream>>>(
            (const uint8_t*)Xb, (const uint8_t*)Wb, bias, out);
    }
}

// Round 27
// 117.434 us; speedup vs baseline: 9.2625x; 1.0049x over previous
//
#include <hip/hip_runtime.h>
#include <stdint.h>

// BinarizeLinear inference: out = sign(X) @ sign(W) + bias
// Round 27: convert occupancy push. r26 showed 66KB LDS -> 2 blocks/CU ->
// block-granular vmcnt(0) drains serialize the memory pipe (1.3 TB/s).
// Tiles halved to ~33KB -> 4 blocks/CU: four independent drain points per
// CU overlap cross-block (m114, no compiler cooperation needed).
// X: 32 rows x 256 k (pitch 1040). W: 64 k x 128 o via per-lane gload
// SOURCE addressing (dest stays linear). Same blocked layout / nibble
// order as r26 (absmax 0). GEMM = r23 exact.

#define N_ROWS 8192
#define K_DIM  4096
#define O_DIM  4096
#define KW     64

typedef int   int4v    __attribute__((ext_vector_type(4)));
typedef int   int8v    __attribute__((ext_vector_type(8)));
typedef float float16v __attribute__((ext_vector_type(16)));

__device__ __forceinline__ int8v mk8u(int4v x) {
    return __builtin_shufflevector(x, x, 0, 1, 2, 3, -1, -1, -1, -1);
}

// fp4 e2m1: +1.0 = 0x2, -1.0 = 0xA
__device__ __forceinline__ uint32_t nib4(float f) { return f > 0.0f ? 0x2u : 0xAu; }

__device__ __forceinline__ uint32_t pack8(const float* f) {
    uint32_t v = 0;
    #pragma unroll
    for (int j = 0; j < 8; ++j) v |= nib4(f[j]) << (4 * j);
    return v;
}

// ====================== X and W -> fp4 blocked, ONE kernel ==================
// X blocks [0,4096): 32 rows x 256 k, LDS pitch 1040 (33280 B total).
// W blocks [4096,6144): 64 k-rows x 128 o, LDS 32 KB linear.
#define XPITCH 1040

__global__ __launch_bounds__(256) void convert_xw_fp4(
        const float* __restrict__ X, const float* __restrict__ W,
        uint8_t* __restrict__ XB, uint8_t* __restrict__ WB) {
    __shared__ uint8_t slds[32 * XPITCH];   // 33280 B -> 4 blocks/CU
    const int tid  = threadIdx.x;
    const int lane = tid & 63;
    const int wid  = tid >> 6;

    if (blockIdx.x < 4096) {
        // ---------------- X: rows r0..r0+31, k in [kq*256, kq*256+256) -----
        const int r0 = (blockIdx.x >> 4) * 32;
        const int kq = blockIdx.x & 15;
        const float* xs = X + (size_t)r0 * K_DIM + kq * 256;

        // phase 1: 8 gload_lds per wave (1KB row each), all in flight
        #pragma unroll
        for (int i = 0; i < 8; ++i) {
            int r = wid * 8 + i;            // 0..31
            __builtin_amdgcn_global_load_lds(
                (const __attribute__((address_space(1))) void*)
                    (xs + (size_t)r * K_DIM + lane * 4),
                (__attribute__((address_space(3))) void*)
                    (slds + r * XPITCH + lane * 16),
                16, 0, 0);
        }
        asm volatile("s_waitcnt vmcnt(0)" ::: "memory");
        __syncthreads();

        // phase 2: 4 pieces (ktl 0..3), one per wave
        const int row31 = lane & 31;
        const int khalf = lane >> 5;
        const int G = r0 >> 8, g = (r0 >> 5) & 7;
        const int ktl = wid;                // 0..3
        const float* src = (const float*)(slds + row31 * XPITCH
                                          + ktl * 256 + khalf * 128);
        float fv[32];
        #pragma unroll
        for (int q = 0; q < 8; ++q)
            *(float4*)(fv + 4 * q) = ((const float4*)src)[q];
        uint32_t ow0 = pack8(fv), ow1 = pack8(fv + 8),
                 ow2 = pack8(fv + 16), ow3 = pack8(fv + 24);
        int4v o; o.x = (int)ow0; o.y = (int)ow1; o.z = (int)ow2; o.w = (int)ow3;
        size_t base = ((size_t)G << 19) + (size_t)(kq * 4 + ktl) * 8192
                    + (size_t)g * 1024;
        *(int4v*)(XB + base + lane * 16) = o;
    } else {
        // ---------------- W: k in [k0,k0+64), o in [o0,o0+128) -------------
        const int wb = (int)blockIdx.x - 4096;   // 0..2047
        const int k0 = (wb >> 5) * 64;
        const int o0 = (wb & 31) * 128;
        const float* ws = W + (size_t)k0 * O_DIM + o0;

        // phase 1: 8 gloads/wave; gload j covers k-rows 2j,2j+1 via per-lane
        // SOURCE addressing (dest linear: j*1024 + lane*16)
        #pragma unroll
        for (int i = 0; i < 8; ++i) {
            int j = wid * 8 + i;            // 0..31
            __builtin_amdgcn_global_load_lds(
                (const __attribute__((address_space(1))) void*)
                    (ws + (size_t)(2 * j + (lane >> 5)) * O_DIM + (lane & 31) * 4),
                (__attribute__((address_space(3))) void*)
                    (slds + j * 1024 + lane * 16),
                16, 0, 0);
        }
        asm volatile("s_waitcnt vmcnt(0)" ::: "memory");
        __syncthreads();

        // phase 2: 4 pieces (g 0..3), one per wave
        const int o31   = lane & 31;
        const int khalf = lane >> 5;
        const int G     = o0 >> 8;
        const int gbase = (o0 >> 5) & 7;    // 0 or 4
        const int kt    = k0 >> 6;
        const int g     = wid;              // 0..3
        const int ol    = g * 32 + o31;     // 0..127
        uint32_t ow[4];
        #pragma unroll
        for (int q = 0; q < 4; ++q) {
            uint32_t v = 0;
            #pragma unroll
            for (int j2 = 0; j2 < 8; ++j2) {
                int kr = khalf * 32 + q * 8 + j2;
                float f = *(const float*)(slds + (kr >> 1) * 1024
                                          + (kr & 1) * 512 + ol * 4);
                v |= nib4(f) << (4 * j2);
            }
            ow[q] = v;
        }
        int4v o; o.x = (int)ow[0]; o.y = (int)ow[1]; o.z = (int)ow[2]; o.w = (int)ow[3];
        size_t base = ((size_t)G << 19) + (size_t)kt * 8192
                    + (size_t)(gbase + g) * 1024;
        *(int4v*)(WB + base + lane * 16) = o;
    }
}

// ====================== 256x128 fp4 GEMM, BK=128, 3-deep pipeline ===========
#define MFMA4(a, b, c)                                                        \
    __builtin_amdgcn_mfma_scale_f32_32x32x64_f8f6f4(                          \
        (a), (b), (c), 4, 4, 0, 0x7F7F7F7F, 0, 0x7F7F7F7F)

__global__ __launch_bounds__(256, 2) void fp4_gemm_kernel(
        const uint8_t* __restrict__ XB, const uint8_t* __restrict__ WB,
        const float* __restrict__ bias, float* __restrict__ out) {
    __shared__ uint8_t lds[3 * 24576];   // 72 KiB: per buf [A 16KB | B 8KB]

    const int tid  = threadIdx.x;
    const int swzb = (blockIdx.x & 7) * 128 + (blockIdx.x >> 3);  // XCD swizzle
    const int brow = (swzb >> 5) * 256;
    const int bcol = (swzb & 31) * 128;

    const int lane = tid & 63;
    const int wid  = tid >> 6;
    const int wrow = (wid >> 1) * 128;   // 2 M-groups
    const int wcol = (wid & 1) * 64;     // 2 N-groups
    const int l31  = lane & 31;
    const int lh   = lane >> 5;

    const int ag0 = (wrow >> 5) * 1024 + lane * 16;          // A piece base
    const int bg0 = 16384 + (wcol >> 5) * 1024 + lane * 16;  // B piece base

    const uint8_t* Asrc = XB + ((size_t)(brow >> 8) << 19) + tid * 16;
    const uint8_t* Bsrc = WB + ((size_t)(bcol >> 8) << 19)
                             + ((bcol & 255) >> 5) * 1024 + tid * 16;

#define GSTAGE(buf, t)                                                        \
    {                                                                         \
        _Pragma("unroll")                                                     \
        for (int j = 0; j < 4; ++j) {                                         \
            __builtin_amdgcn_global_load_lds(                                 \
                (const __attribute__((address_space(1))) void*)               \
                    (Asrc + (size_t)(t) * 16384 + j * 4096),                  \
                (__attribute__((address_space(3))) void*)                     \
                    (lds + (buf) * 24576 + j * 4096 + tid * 16), 16, 0, 0);   \
        }                                                                     \
        _Pragma("unroll")                                                     \
        for (int h = 0; h < 2; ++h) {                                         \
            __builtin_amdgcn_global_load_lds(                                 \
                (const __attribute__((address_space(1))) void*)               \
                    (Bsrc + (size_t)(t) * 16384 + h * 8192),                  \
                (__attribute__((address_space(3))) void*)                     \
                    (lds + (buf) * 24576 + 16384 + h * 4096 + tid * 16),      \
                16, 0, 0);                                                    \
        }                                                                     \
    }

#define LOADH(A0, A1, A2, A3, B0, B1, buf, h)                                 \
    {                                                                         \
        const uint8_t* Ap = lds + (buf) * 24576 + (h) * 8192 + ag0;           \
        const uint8_t* Bp = lds + (buf) * 24576 + (h) * 4096 + bg0;           \
        A0 = mk8u(*(const int4v*)(Ap));                                       \
        A1 = mk8u(*(const int4v*)(Ap + 1024));                                \
        A2 = mk8u(*(const int4v*)(Ap + 2048));                                \
        A3 = mk8u(*(const int4v*)(Ap + 3072));                                \
        B0 = mk8u(*(const int4v*)(Bp));                                       \
        B1 = mk8u(*(const int4v*)(Bp + 1024));                                \
    }

#define MFMA8(A0, A1, A2, A3, B0, B1)                                         \
    {                                                                         \
        __builtin_amdgcn_s_setprio(1);                                        \
        c00 = MFMA4(A0, B0, c00);  c01 = MFMA4(A0, B1, c01);                  \
        c10 = MFMA4(A1, B0, c10);  c11 = MFMA4(A1, B1, c11);                  \
        c20 = MFMA4(A2, B0, c20);  c21 = MFMA4(A2, B1, c21);                  \
        c30 = MFMA4(A3, B0, c30);  c31 = MFMA4(A3, B1, c31);                  \
        __builtin_amdgcn_s_setprio(0);                                        \
    }

#define STEP(bufc, bufs, t, LASTWAIT)                                         \
    {                                                                         \
        if (LASTWAIT) asm volatile("s_waitcnt vmcnt(0)" ::: "memory");        \
        else          asm volatile("s_waitcnt vmcnt(6)" ::: "memory");        \
        __builtin_amdgcn_s_barrier();                                         \
        if ((t) + 2 < 32) GSTAGE(bufs, (t) + 2);                              \
        LOADH(a0, a1, a2, a3, b0, b1, bufc, 0);                               \
        LOADH(na0, na1, na2, na3, nb0, nb1, bufc, 1);                         \
        MFMA8(a0, a1, a2, a3, b0, b1);                                        \
        MFMA8(na0, na1, na2, na3, nb0, nb1);                                  \
    }

    float16v c00 = 0, c01 = 0, c10 = 0, c11 = 0,
             c20 = 0, c21 = 0, c30 = 0, c31 = 0;
    int8v a0, a1, a2, a3, b0, b1;
    int8v na0, na1, na2, na3, nb0, nb1;

    GSTAGE(0, 0);
    GSTAGE(1, 1);

    for (int i = 0; i < 10; ++i) {
        const int t = 3 * i;
        STEP(0, 2, t,     false);
        STEP(1, 0, t + 1, false);
        STEP(2, 1, t + 2, false);
    }
    STEP(0, 2, 30, false);
    STEP(1, 0, 31, true);
#undef STEP
#undef MFMA8
#undef LOADH
#undef GSTAGE

    float bv0 = bias[bcol + wcol + l31];
    float bv1 = bias[bcol + wcol + 32 + l31];
    const size_t obase = (size_t)(brow + wrow) * O_DIM + bcol + wcol;

#define CWRITE(cm, m, n, bv)                                                  \
    {                                                                         \
        _Pragma("unroll")                                                     \
        for (int r = 0; r < 16; ++r) {                                        \
            int rl = (r & 3) + 8 * (r >> 2) + 4 * lh;                         \
            out[obase + (size_t)((m) * 32 + rl) * O_DIM + (n) * 32 + l31] =   \
                cm[r] + (bv);                                                 \
        }                                                                     \
    }

    CWRITE(c00, 0, 0, bv0); CWRITE(c01, 0, 1, bv1);
    CWRITE(c10, 1, 0, bv0); CWRITE(c11, 1, 1, bv1);
    CWRITE(c20, 2, 0, bv0); CWRITE(c21, 2, 1, bv1);
    CWRITE(c30, 3, 0, bv0); CWRITE(c31, 3, 1, bv1);
#undef CWRITE
}

// ====================== popcount fallback (round-5, proven) =================
__global__ __launch_bounds__(256) void pack_x_kernel(
        const float* __restrict__ X, uint64_t* __restrict__ Xb) {
    int wave = (int)((blockIdx.x * blockDim.x + threadIdx.x) >> 6);
    int lane = threadIdx.x & 63;
    if (wave >= N_ROWS) return;
    const float* xr = X + (size_t)wave * K_DIM;
    uint64_t* xbr = Xb + (size_t)wave * KW;
    #pragma unroll 4
    for (int w = 0; w < KW; ++w) {
        float v = xr[w * 64 + lane];
        unsigned long long m = __ballot(v > 0.0f);
        if (lane == 0) xbr[w] = (uint64_t)m;
    }
}

__global__ __launch_bounds__(256) void pack_w_kernel(
        const float* __restrict__ W, uint64_t* __restrict__ Wb) {
    int oc = blockIdx.x & 15;
    int w  = blockIdx.x >> 4;
    int o  = oc * 256 + threadIdx.x;
    const float* wp = W + (size_t)(w * 64) * O_DIM + o;
    uint64_t word = 0;
    #pragma unroll 8
    for (int p = 0; p < 64; ++p) {
        float v = wp[(size_t)p * O_DIM];
        word |= (uint64_t)(v > 0.0f) << p;
    }
    Wb[(size_t)o * KW + w] = word;
}

__global__ __launch_bounds__(256) void xnor_gemm_kernel(
        const uint8_t* __restrict__ Xb, const uint8_t* __restrict__ Wb,
        const float* __restrict__ bias, float* __restrict__ out) {
    __shared__ uint4 lds4[2048];
    const int tid    = threadIdx.x;
    const int brow   = (blockIdx.x >> 5) * 128;
    const int bcol   = (blockIdx.x & 31) * 128;
    const int tx     = tid & 15;
    const int ty     = tid >> 4;
    const int widx   = tid >> 6;
    const int xbase0 = ty * 64 + (ty & 7);
    const int wbase0 = 1024 + tx * 64 + (tx & 7);
    uint32_t acc[8][8] = {};
    for (int kc = 0; kc < 4; ++kc) {
        __syncthreads();
        #pragma unroll
        for (int i = 0; i < 4; ++i) {
            int idx  = tid + 256 * i;
            int row  = idx >> 3;
            int srcc = (idx & 7) ^ ((idx >> 6) & 7);
            size_t goff = ((size_t)row << 9) + (kc << 7) + (srcc << 4);
            __builtin_amdgcn_global_load_lds(
                (const __attribute__((address_space(1))) void*)
                    (Xb + ((size_t)brow << 9) + goff),
                (__attribute__((address_space(3))) void*)
                    (lds4 + i * 256 + widx * 64), 16, 0, 0);
            __builtin_amdgcn_global_load_lds(
                (const __attribute__((address_space(1))) void*)
                    (Wb + ((size_t)bcol << 9) + goff),
                (__attribute__((address_space(3))) void*)
                    (lds4 + 1024 + i * 256 + widx * 64), 16, 0, 0);
        }
        asm volatile("s_waitcnt vmcnt(0)" ::: "memory");
        __syncthreads();
        for (int kq = 0; kq < 8; ++kq) {
            const uint4* xp = &lds4[xbase0 ^ kq];
            const uint4* wp = &lds4[wbase0 ^ kq];
            uint4 xq[8];
            #pragma unroll
            for (int r = 0; r < 8; ++r) xq[r] = xp[8 * r];
            #pragma unroll
            for (int c = 0; c < 8; ++c) {
                uint4 wv = wp[8 * c];
                #pragma unroll
                for (int r = 0; r < 8; ++r) {
                    uint32_t a = acc[r][c];
                    a = __builtin_popcount(xq[r].x ^ wv.x) + a;
                    a = __builtin_popcount(xq[r].y ^ wv.y) + a;
                    a = __builtin_popcount(xq[r].z ^ wv.z) + a;
                    a = __builtin_popcount(xq[r].w ^ wv.w) + a;
                    acc[r][c] = a;
                }
            }
        }
    }
    float bv[8];
    #pragma unroll
    for (int c = 0; c < 8; ++c) bv[c] = bias[bcol + tx * 8 + c];
    #pragma unroll
    for (int r = 0; r < 8; ++r) {
        float vals[8];
        #pragma unroll
        for (int c = 0; c < 8; ++c)
            vals[c] = (float)(K_DIM - 2 * (int)acc[r][c]) + bv[c];
        float4* op = (float4*)(out + (size_t)(brow + ty * 8 + r) * O_DIM
                               + bcol + tx * 8);
        op[0] = make_float4(vals[0], vals[1], vals[2], vals[3]);
        op[1] = make_float4(vals[4], vals[5], vals[6], vals[7]);
    }
}

// ====================== launcher ============================================
extern "C" void kernel_launch(void* const* d_in, const int* in_sizes, int n_in,
                              void* d_out, int out_size, void* d_ws, size_t ws_size,
                              hipStream_t stream) {
    const float* X    = (const float*)d_in[0];
    const float* W    = (const float*)d_in[1];
    const float* bias = (const float*)d_in[2];
    float* out        = (float*)d_out;

    const size_t XB4 = (size_t)N_ROWS * K_DIM / 2;   // 16 MiB fp4 X
    const size_t WB4 = (size_t)O_DIM * K_DIM / 2;    //  8 MiB fp4 W

    if (ws_size >= XB4 + WB4) {
        uint8_t* XBlk = (uint8_t*)d_ws;
        uint8_t* WBlk = (uint8_t*)d_ws + XB4;

        convert_xw_fp4<<<4096 + 2048, 256, 0, stream>>>(X, W, XBlk, WBlk);
        fp4_gemm_kernel<<<(N_ROWS / 256) * (O_DIM / 128), 256, 0, stream>>>(
            XBlk, WBlk, bias, out);
    } else {
        uint64_t* Xb = (uint64_t*)d_ws;
        uint64_t* Wb = (uint64_t*)((uint8_t*)d_ws + (size_t)N_ROWS * KW * 8);
        pack_x_kernel<<<N_ROWS / 4, 256, 0, stream>>>(X, Xb);
        pack_w_kernel<<<16 * 64, 256, 0, stream>>>(W, Wb);
        xnor_gemm_kernel<<<(N_ROWS / 128) * (O_DIM / 128), 256, 0, stream>>>(
            (const uint8_t*)Xb, (const uint8_t*)Wb, bias, out);
    }
}